// Round 11
// baseline (170.085 us; speedup 1.0000x reference)
//
#include <hip/hip_runtime.h>
#include <stdint.h>

typedef __attribute__((ext_vector_type(8))) short short8;
typedef __attribute__((ext_vector_type(4))) short short4v;
typedef __attribute__((ext_vector_type(4))) float f32x4;
typedef __attribute__((ext_vector_type(2))) unsigned int uint2v;

#define B_ 4
#define T_ 2048
#define C_ 1024
#define H_ 16
#define D_ 64
#define C3_ 3072

#define AS1 __attribute__((address_space(1)))
#define AS3 __attribute__((address_space(3)))

#define QK_SCALE 0.18033688f   /* 1/sqrt(64) * log2(e), folded into Q at GEMM1 epilogue */

__device__ __forceinline__ unsigned short f2bf(float f) {
    union { float f; uint32_t u; } v; v.f = f;
    uint32_t r = v.u + 0x7FFFu + ((v.u >> 16) & 1u);
    return (unsigned short)(r >> 16);
}

__device__ __forceinline__ uint32_t pk_bf16(float lo, float hi) {
    uint32_t r;
    asm("v_cvt_pk_bf16_f32 %0, %1, %2" : "=v"(r) : "v"(lo), "v"(hi));
    return r;
}

// ---------------- fp32 -> bf16 elementwise ----------------
__global__ void k_cvt_bf16(const float* __restrict__ in, unsigned short* __restrict__ out, int n4) {
    int i = blockIdx.x * blockDim.x + threadIdx.x;
    if (i >= n4) return;
    float4 v = ((const float4*)in)[i];
    unsigned short o0 = f2bf(v.x), o1 = f2bf(v.y), o2 = f2bf(v.z), o3 = f2bf(v.w);
    unsigned long long packed = (unsigned long long)o0 | ((unsigned long long)o1 << 16)
        | ((unsigned long long)o2 << 32) | ((unsigned long long)o3 << 48);
    *(unsigned long long*)(out + (size_t)i * 4) = packed;
}

// ---------------- W[K][N] fp32 -> WT[N][K] bf16 ----------------
__global__ void k_wtrans(const float* __restrict__ W, unsigned short* __restrict__ WT, int K, int N) {
    __shared__ float t[32][33];
    int n0 = blockIdx.x * 32, k0 = blockIdx.y * 32;
    int tx = threadIdx.x, ty = threadIdx.y; // (32,8)
#pragma unroll
    for (int i = 0; i < 4; ++i)
        t[ty + i * 8][tx] = W[(size_t)(k0 + ty + i * 8) * N + n0 + tx];
    __syncthreads();
#pragma unroll
    for (int i = 0; i < 4; ++i)
        WT[(size_t)(n0 + ty + i * 8) * K + k0 + tx] = f2bf(t[tx][ty + i * 8]);
}

// ---------------- extract V head-major transposed: vt[bh][d][t] ----------------
__global__ void k_prep_vt(const unsigned short* __restrict__ qkv, unsigned short* __restrict__ vt) {
    int bh = blockIdx.y; int b = bh >> 4, h = bh & 15;
    int t0 = blockIdx.x * 64;
    __shared__ unsigned short tile[64][72];
    int tid = threadIdx.x;
    int r = tid >> 3;          // 0..31
    int c = (tid & 7) * 8;     // 0..56
#pragma unroll
    for (int rr = 0; rr < 64; rr += 32) {
        const unsigned short* src = qkv + (size_t)(b * T_ + t0 + r + rr) * C3_ + 2 * C_ + h * D_ + c;
        short8 v = *(const short8*)src;
#pragma unroll
        for (int j = 0; j < 8; ++j) tile[r + rr][c + j] = (unsigned short)v[j];
    }
    __syncthreads();
#pragma unroll
    for (int rr = 0; rr < 64; rr += 32) {
        int d = r + rr;
        short8 sv;
#pragma unroll
        for (int j = 0; j < 8; ++j) sv[j] = (short)tile[c + j][d];
        *(short8*)(vt + (size_t)bh * D_ * T_ + (size_t)d * T_ + t0 + c) = sv;
    }
}

// ---------------- GEMM: C[M][N] = A[M][K](bf16) @ BT[N][K](bf16)^T + bias ----------------
// BM=256, BN=128, BK=64, 512 threads (8 waves: 4M x 2N), per-wave output 64x64.
// 3-buffer LDS pipeline (48KB/buf = 144KB), counted vmcnt(6), raw s_barrier.
// 4-phase K-step (T3+T4 template): per phase {2 gload_lds for t+2 || ds_read subtile}
//   -> barrier -> lgkmcnt(0) -> setprio(1) -> 8 MFMA -> setprio(0) -> barrier.
// Swizzle byte ^= ((row&7)<<4) via pre-swizzled global source (linear LDS dest) — 0 conflicts (r8).
// XCD-chunked block swizzle. OUT_BF16 path scales cols [0,1024) by QK_SCALE.
template<bool OUT_BF16>
__global__ __launch_bounds__(512, 2) void k_gemm_bt(const unsigned short* __restrict__ A,
                                                    const unsigned short* __restrict__ BT,
                                                    const float* __restrict__ bias,
                                                    unsigned short* __restrict__ outb,
                                                    float* __restrict__ outf,
                                                    int M, int N, int K) {
    __shared__ __align__(16) char arena[147456];
    int tid = threadIdx.x;
    int w = tid >> 6, lane = tid & 63;
    int wrow = w >> 1, wcol = w & 1;

    // --- bijective XCD-chunked grid swizzle (grid size always % 8 == 0 here) ---
    int lin = blockIdx.y * gridDim.x + blockIdx.x;
    int nwg8 = (gridDim.x * gridDim.y) >> 3;
    int newlin = (lin & 7) * nwg8 + (lin >> 3);
    int bx = newlin % gridDim.x;
    int by = newlin / gridDim.x;
    int m0 = by * 256, n0 = bx * 128;

    int lr = lane & 15, lg = lane >> 4;

    f32x4 acc[4][4] = {};

    // --- staging source pointers (pre-swizzled global col; linear LDS dest) ---
    int gr = tid >> 3;                                      // base row 0..63
    int scb = ((tid & 7) << 4) ^ (((tid >> 3) & 7) << 4);
    const char* sA[4];
    const char* sB[2];
#pragma unroll
    for (int rr = 0; rr < 4; ++rr)
        sA[rr] = (const char*)A + (size_t)(m0 + gr + rr * 64) * K * 2 + scb;
#pragma unroll
    for (int rr = 0; rr < 2; ++rr)
        sB[rr] = (const char*)BT + (size_t)(n0 + gr + rr * 64) * K * 2 + scb;

    // --- ds_read fragment bases (tile-invariant; +OFS at use) ---
    int inner = (lg * 16) ^ ((lr & 7) << 4);
    int aoff = wrow * 8192 + lr * 128 + inner;            // A frag: +i*2048, k1: ^64
    int boff = 32768 + wcol * 8192 + lr * 128 + inner;    // B frag: +j*2048, k1: ^64

#define GLA(OFS, R) { __builtin_amdgcn_global_load_lds((const AS1 void*)sA[R],                      \
                        (AS3 void*)(arena + (OFS) + tid * 16 + (R) * 8192), 16, 0, 0);              \
                      sA[R] += 128; }
#define GLB(OFS, R) { __builtin_amdgcn_global_load_lds((const AS1 void*)sB[R],                      \
                        (AS3 void*)(arena + (OFS) + 32768 + tid * 16 + (R) * 8192), 16, 0, 0);      \
                      sB[R] += 128; }
#define LDA(OFS, I, KH) (*(const short8*)(arena + (((OFS) + aoff + (I) * 2048) ^ ((KH) * 64))))
#define LDB(OFS, J, KH) (*(const short8*)(arena + (((OFS) + boff + (J) * 2048) ^ ((KH) * 64))))
#define MFMA8(I0, I1, RA0, RA1)                                                                     \
    {                                                                                               \
        __builtin_amdgcn_s_setprio(1);                                                              \
        acc[I0][0] = __builtin_amdgcn_mfma_f32_16x16x32_bf16(RA0, rb0, acc[I0][0], 0, 0, 0);        \
        acc[I0][1] = __builtin_amdgcn_mfma_f32_16x16x32_bf16(RA0, rb1, acc[I0][1], 0, 0, 0);        \
        acc[I0][2] = __builtin_amdgcn_mfma_f32_16x16x32_bf16(RA0, rb2, acc[I0][2], 0, 0, 0);        \
        acc[I0][3] = __builtin_amdgcn_mfma_f32_16x16x32_bf16(RA0, rb3, acc[I0][3], 0, 0, 0);        \
        acc[I1][0] = __builtin_amdgcn_mfma_f32_16x16x32_bf16(RA1, rb0, acc[I1][0], 0, 0, 0);        \
        acc[I1][1] = __builtin_amdgcn_mfma_f32_16x16x32_bf16(RA1, rb1, acc[I1][1], 0, 0, 0);        \
        acc[I1][2] = __builtin_amdgcn_mfma_f32_16x16x32_bf16(RA1, rb2, acc[I1][2], 0, 0, 0);        \
        acc[I1][3] = __builtin_amdgcn_mfma_f32_16x16x32_bf16(RA1, rb3, acc[I1][3], 0, 0, 0);        \
        __builtin_amdgcn_s_setprio(0);                                                              \
    }

    int NT = K >> 6;   // K / 64
    int ofs0 = 0, ofs1 = 49152, ofs2 = 98304;

    // ---- prologue: stage tiles 0 and 1 ----
    GLA(ofs0, 0) GLA(ofs0, 1) GLA(ofs0, 2) GLA(ofs0, 3) GLB(ofs0, 0) GLB(ofs0, 1)
    GLA(ofs1, 0) GLA(ofs1, 1) GLA(ofs1, 2) GLA(ofs1, 3) GLB(ofs1, 0) GLB(ofs1, 1)
    asm volatile("s_waitcnt vmcnt(6)" ::: "memory");   // tile 0 complete (tile 1 in flight)
    __builtin_amdgcn_s_barrier();

    for (int t = 0; t < NT; ++t) {
        bool pf = (t + 2 < NT);
        short8 rb0, rb1, rb2, rb3;
        // ---- phase 0: k0, m-half 0 ----
        if (pf) { GLA(ofs2, 0) GLA(ofs2, 1) }
        {
            short8 ra0 = LDA(ofs0, 0, 0), ra1 = LDA(ofs0, 1, 0);
            rb0 = LDB(ofs0, 0, 0); rb1 = LDB(ofs0, 1, 0); rb2 = LDB(ofs0, 2, 0); rb3 = LDB(ofs0, 3, 0);
            __builtin_amdgcn_s_barrier();
            asm volatile("s_waitcnt lgkmcnt(0)" ::: "memory");
            MFMA8(0, 1, ra0, ra1)
            __builtin_amdgcn_s_barrier();
        }
        // ---- phase 1: k0, m-half 1 ----
        if (pf) { GLA(ofs2, 2) GLA(ofs2, 3) }
        {
            short8 ra0 = LDA(ofs0, 2, 0), ra1 = LDA(ofs0, 3, 0);
            __builtin_amdgcn_s_barrier();
            asm volatile("s_waitcnt lgkmcnt(0)" ::: "memory");
            MFMA8(2, 3, ra0, ra1)
            __builtin_amdgcn_s_barrier();
        }
        // ---- phase 2: k1, m-half 0 ----
        if (pf) { GLB(ofs2, 0) GLB(ofs2, 1) }
        {
            short8 ra0 = LDA(ofs0, 0, 1), ra1 = LDA(ofs0, 1, 1);
            rb0 = LDB(ofs0, 0, 1); rb1 = LDB(ofs0, 1, 1); rb2 = LDB(ofs0, 2, 1); rb3 = LDB(ofs0, 3, 1);
            __builtin_amdgcn_s_barrier();
            asm volatile("s_waitcnt lgkmcnt(0)" ::: "memory");
            MFMA8(0, 1, ra0, ra1)
            __builtin_amdgcn_s_barrier();
        }
        // ---- phase 3: k1, m-half 1 (+ tile-boundary vmcnt) ----
        {
            short8 ra0 = LDA(ofs0, 2, 1), ra1 = LDA(ofs0, 3, 1);
            if (pf) { asm volatile("s_waitcnt vmcnt(6)" ::: "memory"); }
            else    { asm volatile("s_waitcnt vmcnt(0)" ::: "memory"); }
            __builtin_amdgcn_s_barrier();
            asm volatile("s_waitcnt lgkmcnt(0)" ::: "memory");
            MFMA8(2, 3, ra0, ra1)
            __builtin_amdgcn_s_barrier();
        }
        int tmp = ofs0; ofs0 = ofs1; ofs1 = ofs2; ofs2 = tmp;
    }
#undef GLA
#undef GLB
#undef LDA
#undef LDB
#undef MFMA8

    // ---- epilogue: per-wave 64x64 at (wrow*64, wcol*64) ----
#pragma unroll
    for (int i = 0; i < 4; ++i) {
        int row = m0 + wrow * 64 + i * 16 + lg * 4;
#pragma unroll
        for (int j = 0; j < 4; ++j) {
            int col = n0 + wcol * 64 + j * 16 + lr;
            float bv = bias[col];
#pragma unroll
            for (int r = 0; r < 4; ++r) {
                float v = acc[i][j][r] + bv;
                if (OUT_BF16) {
                    if (col < C_) v *= QK_SCALE;   // pre-scale Q columns
                    outb[(size_t)(row + r) * N + col] = f2bf(v);
                } else {
                    outf[(size_t)(row + r) * N + col] = v;
                }
            }
        }
    }
}

// ---------------- causal flash attention (swapped QK^T, no-max softmax) ----------------
// LDS arena layout (bytes):
//   [0,8192)      K buf0      [8192,16384)   K buf1
//   [16384,24576) V buf0      [24576,32768)  V buf1
//   [32768,40960) P per-wave (w*2048), conflict-free half-parity swizzle
__global__ __launch_bounds__(256, 4) void k_attn(const unsigned short* __restrict__ qkv,
                                                 const unsigned short* __restrict__ vt,
                                                 unsigned short* __restrict__ y) {
    __shared__ __align__(16) char arena[40960];
    int tid = threadIdx.x;
    int w = tid >> 6, lane = tid & 63;
    int lr = lane & 15, lg = lane >> 4;

    // bijective XCD-chunk swizzle (1024 % 8 == 0)
    int bid = blockIdx.x;
    int bid2 = (bid & 7) * 128 + (bid >> 3);
    int bh = bid2 >> 4, pair = bid2 & 15;
    int b = bh >> 4, h = bh & 15;

    const unsigned short* kbase = qkv + (size_t)(b * T_) * C3_ + C_ + h * D_;
    const unsigned short* vtb = vt + (size_t)bh * D_ * T_;

    // --- precomputed LDS addresses (tile-invariant) ---
    int sw_ = (lr & 7) << 4;
    int RB0 = lr * 128 + ((lg * 16) ^ sw_);   // K/V frag base (imm: arrayoff + buf + j*2048)
    int RB1 = RB0 ^ 64;
    int jl = (lr >> 1) & 3;
    int pbase = 32768 + w * 2048 + lr * 128
              + ((((lg >> 1) ^ (lr & 1)) << 4) | (((lg & 1) ^ (lr >> 3)) << 3));
    int pwa[4];
#pragma unroll
    for (int j = 0; j < 4; ++j) pwa[j] = pbase + ((j ^ jl) << 5);
    // P A-frag read addresses: XOR for the 64-offset (bit 6 lives inside the
    // swizzled column field — ADDITION WOULD CARRY into the row bits), plus
    // half-swap (+8, never carries: bit 3 of prd0 is 0) baked into the address.
    int prd0 = 32768 + w * 2048 + lr * 128 + ((lg ^ (lr & 7)) << 4);
    int prd1 = prd0 ^ 64;
    int hs = lr & 8;
    int prA0a = prd0 + hs,       prA0b = prd0 + (8 ^ hs);
    int prA1a = prd1 + hs,       prA1b = prd1 + (8 ^ hs);

    // --- global stage sources (loop-carried pointers) ---
    int row0 = tid >> 3, row1 = 32 + (tid >> 3);
    int scol0 = ((tid & 7) << 4) ^ ((row0 & 7) << 4);
    int scol1 = ((tid & 7) << 4) ^ ((row1 & 7) << 4);

    const char *sK0, *sK1, *sV0, *sV1;

#define ASTAGE(LDSOFF)                                                                                  \
    {                                                                                                   \
        __builtin_amdgcn_global_load_lds((const AS1 void*)sK0, (AS3 void*)(arena + (LDSOFF) + w * 1024), 16, 0, 0);          \
        __builtin_amdgcn_global_load_lds((const AS1 void*)sK1, (AS3 void*)(arena + (LDSOFF) + 4096 + w * 1024), 16, 0, 0);   \
        __builtin_amdgcn_global_load_lds((const AS1 void*)sV0, (AS3 void*)(arena + 16384 + (LDSOFF) + w * 1024), 16, 0, 0);  \
        __builtin_amdgcn_global_load_lds((const AS1 void*)sV1, (AS3 void*)(arena + 16384 + (LDSOFF) + 4096 + w * 1024), 16, 0, 0); \
        sK0 += 64 * C3_ * 2; sK1 += 64 * C3_ * 2; sV0 += 128; sV1 += 128;                               \
    }

#define ACOMPUTE(LDSOFF, KT)                                                                            \
    {                                                                                                   \
        f32x4 s[4];                                                                                     \
        __builtin_amdgcn_s_setprio(1);                                                                  \
        _Pragma("unroll")                                                                               \
        for (int j = 0; j < 4; ++j) {                                                                   \
            short8 kf0 = *(const short8*)(arena + RB0 + (LDSOFF) + j * 2048);                           \
            short8 kf1 = *(const short8*)(arena + RB1 + (LDSOFF) + j * 2048);                           \
            f32x4 z = {};                                                                               \
            z = __builtin_amdgcn_mfma_f32_16x16x32_bf16(kf0, qf0, z, 0, 0, 0);                          \
            s[j] = __builtin_amdgcn_mfma_f32_16x16x32_bf16(kf1, qf1, z, 0, 0, 0);                       \
        }                                                                                               \
        __builtin_amdgcn_s_setprio(0);                                                                  \
        if ((KT) == ntiles - 1) {                                                                       \
            int kb = (KT) * 64 + lg * 4 - qv;                                                           \
            _Pragma("unroll")                                                                           \
            for (int j = 0; j < 4; ++j)                                                                 \
                _Pragma("unroll")                                                                       \
                for (int r = 0; r < 4; ++r)                                                             \
                    if (kb + j * 16 + r > 0) s[j][r] = -INFINITY;                                       \
        }                                                                                               \
        _Pragma("unroll")                                                                               \
        for (int j = 0; j < 4; ++j)                                                                     \
            _Pragma("unroll")                                                                           \
            for (int r = 0; r < 4; ++r) {                                                               \
                float pv = __builtin_amdgcn_exp2f(s[j][r]);                                             \
                s[j][r] = pv;                                                                           \
                ls += pv;                                                                               \
            }                                                                                           \
        _Pragma("unroll")                                                                               \
        for (int j = 0; j < 4; ++j) {                                                                   \
            uint2v W;                                                                                   \
            W[0] = pk_bf16(s[j][0], s[j][1]);                                                           \
            W[1] = pk_bf16(s[j][2], s[j][3]);                                                           \
            *(uint2v*)(arena + pwa[j]) = W;                                                             \
        }                                                                                               \
        short4v l0 = *(const short4v*)(arena + prA0a);                                                  \
        short4v h0 = *(const short4v*)(arena + prA0b);                                                  \
        short4v l1 = *(const short4v*)(arena + prA1a);                                                  \
        short4v h1 = *(const short4v*)(arena + prA1b);                                                  \
        short8 pa0 = __builtin_shufflevector(l0, h0, 0, 1, 2, 3, 4, 5, 6, 7);                           \
        short8 pa1 = __builtin_shufflevector(l1, h1, 0, 1, 2, 3, 4, 5, 6, 7);                           \
        __builtin_amdgcn_s_setprio(1);                                                                  \
        _Pragma("unroll")                                                                               \
        for (int dt = 0; dt < 4; ++dt) {                                                                \
            short8 vf0 = *(const short8*)(arena + RB0 + 16384 + (LDSOFF) + dt * 2048);                  \
            short8 vf1 = *(const short8*)(arena + RB1 + 16384 + (LDSOFF) + dt * 2048);                  \
            o[dt] = __builtin_amdgcn_mfma_f32_16x16x32_bf16(pa0, vf0, o[dt], 0, 0, 0);                  \
            o[dt] = __builtin_amdgcn_mfma_f32_16x16x32_bf16(pa1, vf1, o[dt], 0, 0, 0);                  \
        }                                                                                               \
        __builtin_amdgcn_s_setprio(0);                                                                  \
    }

#pragma unroll 1
    for (int half = 0; half < 2; ++half) {
        int qt = half ? (31 - pair) : pair;
        int q0 = qt * 64;
        int ntiles = qt + 1;

        const unsigned short* qrow = qkv + (size_t)(b * T_ + q0 + w * 16 + lr) * C3_ + h * D_;
        short8 qf0 = *(const short8*)(qrow + lg * 8);
        short8 qf1 = *(const short8*)(qrow + 32 + lg * 8);

        f32x4 o[4] = {};
        float ls = 0.f;    // in-lane partial of unnormalized row-sum (q = q0 + w*16 + lr)
        int qv = q0 + w * 16 + lr;

        sK0 = (const char*)(kbase + (size_t)row0 * C3_) + scol0;
        sK1 = (const char*)(kbase + (size_t)row1 * C3_) + scol1;
        sV0 = (const char*)(vtb + (size_t)row0 * T_) + scol0;
        sV1 = (const char*)(vtb + (size_t)row1 * T_) + scol1;

        ASTAGE(0);
        asm volatile("s_waitcnt vmcnt(0)" ::: "memory");
        __syncthreads();

#pragma unroll 1
        for (int kt = 0; kt < ntiles; kt += 2) {
            if (kt + 1 < ntiles) ASTAGE(8192);
            ACOMPUTE(0, kt);
            asm volatile("s_waitcnt vmcnt(0)" ::: "memory");
            __syncthreads();
            if (kt + 1 < ntiles) {
                if (kt + 2 < ntiles) ASTAGE(0);
                ACOMPUTE(8192, kt + 1);
                asm volatile("s_waitcnt vmcnt(0)" ::: "memory");
                __syncthreads();
            }
        }

        // ---- combine lg-partials of ls, normalize + store ----
        ls += __shfl_xor(ls, 16);
        ls += __shfl_xor(ls, 32);
#pragma unroll
        for (int r = 0; r < 4; ++r) {
            float lst = __shfl(ls, lg * 4 + r, 64);
            float inv = 1.0f / lst;
            int q = q0 + w * 16 + lg * 4 + r;
            unsigned short* yrow = y + (size_t)(b * T_ + q) * C_ + h * D_;
#pragma unroll
            for (int dt = 0; dt < 4; ++dt)
                yrow[dt * 16 + lr] = f2bf(o[dt][r] * inv);
        }
    }
#undef ASTAGE
#undef ACOMPUTE
}

extern "C" void kernel_launch(void* const* d_in, const int* in_sizes, int n_in,
                              void* d_out, int out_size, void* d_ws, size_t ws_size,
                              hipStream_t stream) {
    const float* x  = (const float*)d_in[0];
    const float* Wa = (const float*)d_in[1];
    const float* ba = (const float*)d_in[2];
    const float* Wp = (const float*)d_in[3];
    const float* bp = (const float*)d_in[4];
    float* out = (float*)d_out;

    char* ws = (char*)d_ws;
    unsigned short* xb  = (unsigned short*)(ws);                       // 16 MB
    unsigned short* wat = (unsigned short*)(ws + 16777216);            // 6 MB
    unsigned short* wpt = (unsigned short*)(ws + 23068672);            // 2 MB
    unsigned short* qkv = (unsigned short*)(ws + 25165824);            // 48 MB
    unsigned short* vt  = (unsigned short*)(ws + 75497472);            // 16 MB
    unsigned short* y   = xb;  // xb dead after GEMM1; reuse for attention output

    // x -> bf16
    k_cvt_bf16<<<8192, 256, 0, stream>>>(x, xb, (B_ * T_ * C_) / 4);
    // weights -> bf16 transposed
    k_wtrans<<<dim3(C3_ / 32, C_ / 32), dim3(32, 8), 0, stream>>>(Wa, wat, C_, C3_);
    k_wtrans<<<dim3(C_ / 32, C_ / 32), dim3(32, 8), 0, stream>>>(Wp, wpt, C_, C_);
    // qkv = x @ W_attn + b_attn   (bf16 out, Q pre-scaled)
    k_gemm_bt<true><<<dim3(C3_ / 128, (B_ * T_) / 256), 512, 0, stream>>>(
        xb, wat, ba, qkv, nullptr, B_ * T_, C3_, C_);
    // v -> vt[bh][d][t]
    k_prep_vt<<<dim3(T_ / 64, B_ * H_), 256, 0, stream>>>(qkv, vt);
    // attention
    k_attn<<<1024, 256, 0, stream>>>(qkv, vt, y);
    // out = y @ W_proj + b_proj   (fp32 out)
    k_gemm_bt<false><<<dim3(C_ / 128, (B_ * T_) / 256), 512, 0, stream>>>(
        y, wpt, bp, nullptr, out, B_ * T_, C_, C_);
}

// Round 12
// 169.458 us; speedup vs baseline: 1.0037x; 1.0037x over previous
//
#include <hip/hip_runtime.h>
#include <stdint.h>

typedef __attribute__((ext_vector_type(8))) short short8;
typedef __attribute__((ext_vector_type(4))) short short4v;
typedef __attribute__((ext_vector_type(4))) float f32x4;
typedef __attribute__((ext_vector_type(2))) unsigned int uint2v;

#define B_ 4
#define T_ 2048
#define C_ 1024
#define H_ 16
#define D_ 64
#define C3_ 3072

#define AS1 __attribute__((address_space(1)))
#define AS3 __attribute__((address_space(3)))

#define QK_SCALE 0.18033688f   /* 1/sqrt(64) * log2(e), folded into Q at GEMM1 epilogue */

__device__ __forceinline__ unsigned short f2bf(float f) {
    union { float f; uint32_t u; } v; v.f = f;
    uint32_t r = v.u + 0x7FFFu + ((v.u >> 16) & 1u);
    return (unsigned short)(r >> 16);
}

__device__ __forceinline__ uint32_t pk_bf16(float lo, float hi) {
    uint32_t r;
    asm("v_cvt_pk_bf16_f32 %0, %1, %2" : "=v"(r) : "v"(lo), "v"(hi));
    return r;
}

// ---------------- fp32 -> bf16 elementwise ----------------
__global__ void k_cvt_bf16(const float* __restrict__ in, unsigned short* __restrict__ out, int n4) {
    int i = blockIdx.x * blockDim.x + threadIdx.x;
    if (i >= n4) return;
    float4 v = ((const float4*)in)[i];
    unsigned short o0 = f2bf(v.x), o1 = f2bf(v.y), o2 = f2bf(v.z), o3 = f2bf(v.w);
    unsigned long long packed = (unsigned long long)o0 | ((unsigned long long)o1 << 16)
        | ((unsigned long long)o2 << 32) | ((unsigned long long)o3 << 48);
    *(unsigned long long*)(out + (size_t)i * 4) = packed;
}

// ---------------- W[K][N] fp32 -> WT[N][K] bf16 ----------------
__global__ void k_wtrans(const float* __restrict__ W, unsigned short* __restrict__ WT, int K, int N) {
    __shared__ float t[32][33];
    int n0 = blockIdx.x * 32, k0 = blockIdx.y * 32;
    int tx = threadIdx.x, ty = threadIdx.y; // (32,8)
#pragma unroll
    for (int i = 0; i < 4; ++i)
        t[ty + i * 8][tx] = W[(size_t)(k0 + ty + i * 8) * N + n0 + tx];
    __syncthreads();
#pragma unroll
    for (int i = 0; i < 4; ++i)
        WT[(size_t)(n0 + ty + i * 8) * K + k0 + tx] = f2bf(t[tx][ty + i * 8]);
}

// ---------------- extract V head-major transposed: vt[bh][d][t] ----------------
__global__ void k_prep_vt(const unsigned short* __restrict__ qkv, unsigned short* __restrict__ vt) {
    int bh = blockIdx.y; int b = bh >> 4, h = bh & 15;
    int t0 = blockIdx.x * 64;
    __shared__ unsigned short tile[64][72];
    int tid = threadIdx.x;
    int r = tid >> 3;          // 0..31
    int c = (tid & 7) * 8;     // 0..56
#pragma unroll
    for (int rr = 0; rr < 64; rr += 32) {
        const unsigned short* src = qkv + (size_t)(b * T_ + t0 + r + rr) * C3_ + 2 * C_ + h * D_ + c;
        short8 v = *(const short8*)src;
#pragma unroll
        for (int j = 0; j < 8; ++j) tile[r + rr][c + j] = (unsigned short)v[j];
    }
    __syncthreads();
#pragma unroll
    for (int rr = 0; rr < 64; rr += 32) {
        int d = r + rr;
        short8 sv;
#pragma unroll
        for (int j = 0; j < 8; ++j) sv[j] = (short)tile[c + j][d];
        *(short8*)(vt + (size_t)bh * D_ * T_ + (size_t)d * T_ + t0 + c) = sv;
    }
}

// ---------------- GEMM: C[M][N] = A[M][K](bf16) @ BT[N][K](bf16)^T + bias ----------------
// BM=256, BN=128, BK=32, 256 threads (4 waves: 2M x 2N), per-wave output 128x64.
// 3-buffer LDS pipeline (24KB/buf = 72KB -> 2 blocks/CU), counted vmcnt(6), raw s_barrier.
// Swizzle for 64B rows: slot ^= ((row>>1)&3)  [quad = (4*lr + swz) mod 8 -> 2 lanes/quad, free]
// applied via pre-swizzled global source (linear LDS dest).
// XCD-chunked block swizzle. OUT_BF16 path scales cols [0,1024) by QK_SCALE.
template<bool OUT_BF16>
__global__ __launch_bounds__(256, 2) void k_gemm_bt(const unsigned short* __restrict__ A,
                                                    const unsigned short* __restrict__ BT,
                                                    const float* __restrict__ bias,
                                                    unsigned short* __restrict__ outb,
                                                    float* __restrict__ outf,
                                                    int M, int N, int K) {
    __shared__ __align__(16) char arena[73728];
    int tid = threadIdx.x;
    int w = tid >> 6, lane = tid & 63;
    int wrow = w >> 1, wcol = w & 1;

    // --- bijective XCD-chunked grid swizzle (grid size always % 8 == 0 here) ---
    int lin = blockIdx.y * gridDim.x + blockIdx.x;
    int nwg8 = (gridDim.x * gridDim.y) >> 3;
    int newlin = (lin & 7) * nwg8 + (lin >> 3);
    int bx = newlin % gridDim.x;
    int by = newlin / gridDim.x;
    int m0 = by * 256, n0 = bx * 128;

    int lr = lane & 15, lg = lane >> 4;

    f32x4 acc[8][4] = {};

    // --- staging source pointers (pre-swizzled global col; linear LDS dest) ---
    // A tile 256x32 bf16 = 16KB -> 4 loads/thread; B tile 128x32 = 8KB -> 2 loads.
    int grow = tid >> 2;                                    // 0..63
    int scb = ((tid & 3) << 4) ^ (((tid >> 3) & 3) << 4);   // swizzled col byte: slot ^ ((row>>1)&3)
    const char* sA[4];
    const char* sB[2];
#pragma unroll
    for (int rr = 0; rr < 4; ++rr)
        sA[rr] = (const char*)A + (size_t)(m0 + grow + rr * 64) * K * 2 + scb;
#pragma unroll
    for (int rr = 0; rr < 2; ++rr)
        sB[rr] = (const char*)BT + (size_t)(n0 + grow + rr * 64) * K * 2 + scb;

    // --- ds_read fragment bases (tile-invariant; +OFS at use) ---
    int inner = (lg * 16) ^ (((lr >> 1) & 3) << 4);
    int aoff = wrow * 8192 + lr * 64 + inner;           // A frag: +i*1024
    int boff = 16384 + wcol * 4096 + lr * 64 + inner;   // B frag: +j*1024

#define GSTAGE(OFS)                                                                                 \
    {                                                                                               \
        _Pragma("unroll")                                                                           \
        for (int rr = 0; rr < 4; ++rr) {                                                            \
            __builtin_amdgcn_global_load_lds((const AS1 void*)sA[rr],                               \
                (AS3 void*)(arena + (OFS) + tid * 16 + rr * 4096), 16, 0, 0);                       \
            sA[rr] += 64;                                                                           \
        }                                                                                           \
        _Pragma("unroll")                                                                           \
        for (int rr = 0; rr < 2; ++rr) {                                                            \
            __builtin_amdgcn_global_load_lds((const AS1 void*)sB[rr],                               \
                (AS3 void*)(arena + (OFS) + 16384 + tid * 16 + rr * 4096), 16, 0, 0);               \
            sB[rr] += 64;                                                                           \
        }                                                                                           \
    }

#define GCOMPUTE(OFS)                                                                               \
    {                                                                                               \
        short8 af[8], bf[4];                                                                        \
        _Pragma("unroll")                                                                           \
        for (int i = 0; i < 8; ++i)                                                                 \
            af[i] = *(const short8*)(arena + (OFS) + aoff + i * 1024);                              \
        _Pragma("unroll")                                                                           \
        for (int j = 0; j < 4; ++j)                                                                 \
            bf[j] = *(const short8*)(arena + (OFS) + boff + j * 1024);                              \
        __builtin_amdgcn_s_setprio(1);                                                              \
        _Pragma("unroll")                                                                           \
        for (int i = 0; i < 8; ++i)                                                                 \
            _Pragma("unroll")                                                                       \
            for (int j = 0; j < 4; ++j)                                                             \
                acc[i][j] = __builtin_amdgcn_mfma_f32_16x16x32_bf16(af[i], bf[j], acc[i][j], 0, 0, 0); \
        __builtin_amdgcn_s_setprio(0);                                                              \
    }

    int NT = K >> 5;   // K / 32
    int ofs0 = 0, ofs1 = 24576, ofs2 = 49152;

    GSTAGE(ofs0);
    GSTAGE(ofs1);
    asm volatile("s_waitcnt vmcnt(6)" ::: "memory");   // tile 0 complete (tile 1 in flight)
    __builtin_amdgcn_s_barrier();
    __builtin_amdgcn_sched_barrier(0);

    for (int t = 0; t < NT; ++t) {
        bool pf = (t + 2 < NT);
        if (pf) GSTAGE(ofs2);
        GCOMPUTE(ofs0);
        if (pf) { asm volatile("s_waitcnt vmcnt(6)" ::: "memory"); }
        else    { asm volatile("s_waitcnt vmcnt(0)" ::: "memory"); }
        __builtin_amdgcn_s_barrier();
        __builtin_amdgcn_sched_barrier(0);
        int tmp = ofs0; ofs0 = ofs1; ofs1 = ofs2; ofs2 = tmp;
    }
#undef GSTAGE
#undef GCOMPUTE

    // ---- epilogue: per-wave 128x64 at (wrow*128, wcol*64) ----
#pragma unroll
    for (int i = 0; i < 8; ++i) {
        int row = m0 + wrow * 128 + i * 16 + lg * 4;
#pragma unroll
        for (int j = 0; j < 4; ++j) {
            int col = n0 + wcol * 64 + j * 16 + lr;
            float bv = bias[col];
#pragma unroll
            for (int r = 0; r < 4; ++r) {
                float v = acc[i][j][r] + bv;
                if (OUT_BF16) {
                    if (col < C_) v *= QK_SCALE;   // pre-scale Q columns
                    outb[(size_t)(row + r) * N + col] = f2bf(v);
                } else {
                    outf[(size_t)(row + r) * N + col] = v;
                }
            }
        }
    }
}

// ---------------- causal flash attention (swapped QK^T, no-max softmax) ----------------
// LDS arena layout (bytes):
//   [0,24576)       K bufs 0/1/2  (8KB each)
//   [24576,49152)   V bufs 0/1/2  (8KB each)
//   [49152,57344)   P per-wave (w*2048), conflict-free half-parity swizzle
// 3-deep pipeline, counted vmcnt(4), raw s_barrier (rounds-8/10 proven protocol).
__global__ __launch_bounds__(256, 2) void k_attn(const unsigned short* __restrict__ qkv,
                                                 const unsigned short* __restrict__ vt,
                                                 unsigned short* __restrict__ y) {
    __shared__ __align__(16) char arena[57344];
    int tid = threadIdx.x;
    int w = tid >> 6, lane = tid & 63;
    int lr = lane & 15, lg = lane >> 4;

    // bijective XCD-chunk swizzle (1024 % 8 == 0)
    int bid = blockIdx.x;
    int bid2 = (bid & 7) * 128 + (bid >> 3);
    int bh = bid2 >> 4, pair = bid2 & 15;
    int b = bh >> 4, h = bh & 15;

    const unsigned short* kbase = qkv + (size_t)(b * T_) * C3_ + C_ + h * D_;
    const unsigned short* vtb = vt + (size_t)bh * D_ * T_;

    // --- precomputed LDS addresses (tile-invariant) ---
    int sw_ = (lr & 7) << 4;
    int RB0 = lr * 128 + ((lg * 16) ^ sw_);   // K/V frag base (+KOFS, V: +24576)
    int RB1 = RB0 ^ 64;
    int jl = (lr >> 1) & 3;
    int pbase = 49152 + w * 2048 + lr * 128
              + ((((lg >> 1) ^ (lr & 1)) << 4) | (((lg & 1) ^ (lr >> 3)) << 3));
    int pwa[4];
#pragma unroll
    for (int j = 0; j < 4; ++j) pwa[j] = pbase + ((j ^ jl) << 5);
    // P A-frag read addresses: XOR for the 64-offset (bit 6 lives inside the
    // swizzled column field — ADDITION WOULD CARRY into the row bits), plus
    // half-swap (+8, never carries: bit 3 of prd0 is 0) baked into the address.
    int prd0 = 49152 + w * 2048 + lr * 128 + ((lg ^ (lr & 7)) << 4);
    int prd1 = prd0 ^ 64;
    int hs = lr & 8;
    int prA0a = prd0 + hs,       prA0b = prd0 + (8 ^ hs);
    int prA1a = prd1 + hs,       prA1b = prd1 + (8 ^ hs);

    // --- global stage sources (loop-carried pointers) ---
    int row0 = tid >> 3, row1 = 32 + (tid >> 3);
    int scol0 = ((tid & 7) << 4) ^ ((row0 & 7) << 4);
    int scol1 = ((tid & 7) << 4) ^ ((row1 & 7) << 4);

    const char *sK0, *sK1, *sV0, *sV1;

#define ASTAGE(KOFS)                                                                                    \
    {                                                                                                   \
        __builtin_amdgcn_global_load_lds((const AS1 void*)sK0, (AS3 void*)(arena + (KOFS) + w * 1024), 16, 0, 0);            \
        __builtin_amdgcn_global_load_lds((const AS1 void*)sK1, (AS3 void*)(arena + (KOFS) + 4096 + w * 1024), 16, 0, 0);     \
        __builtin_amdgcn_global_load_lds((const AS1 void*)sV0, (AS3 void*)(arena + 24576 + (KOFS) + w * 1024), 16, 0, 0);    \
        __builtin_amdgcn_global_load_lds((const AS1 void*)sV1, (AS3 void*)(arena + 24576 + (KOFS) + 4096 + w * 1024), 16, 0, 0); \
        sK0 += 64 * C3_ * 2; sK1 += 64 * C3_ * 2; sV0 += 128; sV1 += 128;                               \
    }

#define ACOMPUTE(KOFS, KT)                                                                              \
    {                                                                                                   \
        f32x4 s[4];                                                                                     \
        __builtin_amdgcn_s_setprio(1);                                                                  \
        _Pragma("unroll")                                                                               \
        for (int j = 0; j < 4; ++j) {                                                                   \
            short8 kf0 = *(const short8*)(arena + RB0 + (KOFS) + j * 2048);                             \
            short8 kf1 = *(const short8*)(arena + RB1 + (KOFS) + j * 2048);                             \
            f32x4 z = {};                                                                               \
            z = __builtin_amdgcn_mfma_f32_16x16x32_bf16(kf0, qf0, z, 0, 0, 0);                          \
            s[j] = __builtin_amdgcn_mfma_f32_16x16x32_bf16(kf1, qf1, z, 0, 0, 0);                       \
        }                                                                                               \
        __builtin_amdgcn_s_setprio(0);                                                                  \
        if ((KT) == ntiles - 1) {                                                                       \
            int kb = (KT) * 64 + lg * 4 - qv;                                                           \
            _Pragma("unroll")                                                                           \
            for (int j = 0; j < 4; ++j)                                                                 \
                _Pragma("unroll")                                                                       \
                for (int r = 0; r < 4; ++r)                                                             \
                    if (kb + j * 16 + r > 0) s[j][r] = -INFINITY;                                       \
        }                                                                                               \
        _Pragma("unroll")                                                                               \
        for (int j = 0; j < 4; ++j)                                                                     \
            _Pragma("unroll")                                                                           \
            for (int r = 0; r < 4; ++r) {                                                               \
                float pv = __builtin_amdgcn_exp2f(s[j][r]);                                             \
                s[j][r] = pv;                                                                           \
                ls += pv;                                                                               \
            }                                                                                           \
        _Pragma("unroll")                                                                               \
        for (int j = 0; j < 4; ++j) {                                                                   \
            uint2v W;                                                                                   \
            W[0] = pk_bf16(s[j][0], s[j][1]);                                                           \
            W[1] = pk_bf16(s[j][2], s[j][3]);                                                           \
            *(uint2v*)(arena + pwa[j]) = W;                                                             \
        }                                                                                               \
        short4v l0 = *(const short4v*)(arena + prA0a);                                                  \
        short4v h0 = *(const short4v*)(arena + prA0b);                                                  \
        short4v l1 = *(const short4v*)(arena + prA1a);                                                  \
        short4v h1 = *(const short4v*)(arena + prA1b);                                                  \
        short8 pa0 = __builtin_shufflevector(l0, h0, 0, 1, 2, 3, 4, 5, 6, 7);                           \
        short8 pa1 = __builtin_shufflevector(l1, h1, 0, 1, 2, 3, 4, 5, 6, 7);                           \
        __builtin_amdgcn_s_setprio(1);                                                                  \
        _Pragma("unroll")                                                                               \
        for (int dt = 0; dt < 4; ++dt) {                                                                \
            short8 vf0 = *(const short8*)(arena + RB0 + 24576 + (KOFS) + dt * 2048);                    \
            short8 vf1 = *(const short8*)(arena + RB1 + 24576 + (KOFS) + dt * 2048);                    \
            o[dt] = __builtin_amdgcn_mfma_f32_16x16x32_bf16(pa0, vf0, o[dt], 0, 0, 0);                  \
            o[dt] = __builtin_amdgcn_mfma_f32_16x16x32_bf16(pa1, vf1, o[dt], 0, 0, 0);                  \
        }                                                                                               \
        __builtin_amdgcn_s_setprio(0);                                                                  \
    }

#pragma unroll 1
    for (int half = 0; half < 2; ++half) {
        int qt = half ? (31 - pair) : pair;
        int q0 = qt * 64;
        int ntiles = qt + 1;

        const unsigned short* qrow = qkv + (size_t)(b * T_ + q0 + w * 16 + lr) * C3_ + h * D_;
        short8 qf0 = *(const short8*)(qrow + lg * 8);
        short8 qf1 = *(const short8*)(qrow + 32 + lg * 8);

        f32x4 o[4] = {};
        float ls = 0.f;    // in-lane partial of unnormalized row-sum (q = q0 + w*16 + lr)
        int qv = q0 + w * 16 + lr;

        sK0 = (const char*)(kbase + (size_t)row0 * C3_) + scol0;
        sK1 = (const char*)(kbase + (size_t)row1 * C3_) + scol1;
        sV0 = (const char*)(vtb + (size_t)row0 * T_) + scol0;
        sV1 = (const char*)(vtb + (size_t)row1 * T_) + scol1;

        int kofs0 = 0, kofs1 = 8192, kofs2 = 16384;

        // ---- prologue: stage tiles 0 and 1 ----
        ASTAGE(kofs0);
        if (ntiles > 1) {
            ASTAGE(kofs1);
            asm volatile("s_waitcnt vmcnt(4)" ::: "memory");   // tile 0 done (tile 1 in flight)
        } else {
            asm volatile("s_waitcnt vmcnt(0)" ::: "memory");
        }
        __builtin_amdgcn_s_barrier();
        __builtin_amdgcn_sched_barrier(0);

#pragma unroll 1
        for (int kt = 0; kt < ntiles; ++kt) {
            bool pf = (kt + 2 < ntiles);
            if (pf) ASTAGE(kofs2);
            ACOMPUTE(kofs0, kt);
            if (pf) { asm volatile("s_waitcnt vmcnt(4)" ::: "memory"); }
            else    { asm volatile("s_waitcnt vmcnt(0)" ::: "memory"); }
            __builtin_amdgcn_s_barrier();
            __builtin_amdgcn_sched_barrier(0);
            int tmp = kofs0; kofs0 = kofs1; kofs1 = kofs2; kofs2 = tmp;
        }

        // ---- combine lg-partials of ls, normalize + store ----
        ls += __shfl_xor(ls, 16);
        ls += __shfl_xor(ls, 32);
#pragma unroll
        for (int r = 0; r < 4; ++r) {
            float lst = __shfl(ls, lg * 4 + r, 64);
            float inv = 1.0f / lst;
            int q = q0 + w * 16 + lg * 4 + r;
            unsigned short* yrow = y + (size_t)(b * T_ + q) * C_ + h * D_;
#pragma unroll
            for (int dt = 0; dt < 4; ++dt)
                yrow[dt * 16 + lr] = f2bf(o[dt][r] * inv);
        }
    }
#undef ASTAGE
#undef ACOMPUTE
}

extern "C" void kernel_launch(void* const* d_in, const int* in_sizes, int n_in,
                              void* d_out, int out_size, void* d_ws, size_t ws_size,
                              hipStream_t stream) {
    const float* x  = (const float*)d_in[0];
    const float* Wa = (const float*)d_in[1];
    const float* ba = (const float*)d_in[2];
    const float* Wp = (const float*)d_in[3];
    const float* bp = (const float*)d_in[4];
    float* out = (float*)d_out;

    char* ws = (char*)d_ws;
    unsigned short* xb  = (unsigned short*)(ws);                       // 16 MB
    unsigned short* wat = (unsigned short*)(ws + 16777216);            // 6 MB
    unsigned short* wpt = (unsigned short*)(ws + 23068672);            // 2 MB
    unsigned short* qkv = (unsigned short*)(ws + 25165824);            // 48 MB
    unsigned short* vt  = (unsigned short*)(ws + 75497472);            // 16 MB
    unsigned short* y   = xb;  // xb dead after GEMM1; reuse for attention output

    // x -> bf16
    k_cvt_bf16<<<8192, 256, 0, stream>>>(x, xb, (B_ * T_ * C_) / 4);
    // weights -> bf16 transposed
    k_wtrans<<<dim3(C3_ / 32, C_ / 32), dim3(32, 8), 0, stream>>>(Wa, wat, C_, C3_);
    k_wtrans<<<dim3(C_ / 32, C_ / 32), dim3(32, 8), 0, stream>>>(Wp, wpt, C_, C_);
    // qkv = x @ W_attn + b_attn   (bf16 out, Q pre-scaled)
    k_gemm_bt<true><<<dim3(C3_ / 128, (B_ * T_) / 256), 256, 0, stream>>>(
        xb, wat, ba, qkv, nullptr, B_ * T_, C3_, C_);
    // v -> vt[bh][d][t]
    k_prep_vt<<<dim3(T_ / 64, B_ * H_), 256, 0, stream>>>(qkv, vt);
    // attention
    k_attn<<<1024, 256, 0, stream>>>(qkv, vt, y);
    // out = y @ W_proj + b_proj   (fp32 out)
    k_gemm_bt<false><<<dim3(C_ / 128, (B_ * T_) / 256), 256, 0, stream>>>(
        y, wpt, bp, nullptr, out, B_ * T_, C_, C_);
}

// Round 13
// 158.794 us; speedup vs baseline: 1.0711x; 1.0672x over previous
//
#include <hip/hip_runtime.h>
#include <stdint.h>

typedef __attribute__((ext_vector_type(8))) short short8;
typedef __attribute__((ext_vector_type(4))) short short4v;
typedef __attribute__((ext_vector_type(4))) float f32x4;
typedef __attribute__((ext_vector_type(2))) unsigned int uint2v;

#define B_ 4
#define T_ 2048
#define C_ 1024
#define H_ 16
#define D_ 64
#define C3_ 3072

#define AS1 __attribute__((address_space(1)))
#define AS3 __attribute__((address_space(3)))

#define QK_SCALE 0.18033688f   /* 1/sqrt(64) * log2(e), folded into Q at GEMM1 epilogue */

__device__ __forceinline__ unsigned short f2bf(float f) {
    union { float f; uint32_t u; } v; v.f = f;
    uint32_t r = v.u + 0x7FFFu + ((v.u >> 16) & 1u);
    return (unsigned short)(r >> 16);
}

__device__ __forceinline__ uint32_t pk_bf16(float lo, float hi) {
    uint32_t r;
    asm("v_cvt_pk_bf16_f32 %0, %1, %2" : "=v"(r) : "v"(lo), "v"(hi));
    return r;
}

// ---------------- fp32 -> bf16 elementwise ----------------
__global__ void k_cvt_bf16(const float* __restrict__ in, unsigned short* __restrict__ out, int n4) {
    int i = blockIdx.x * blockDim.x + threadIdx.x;
    if (i >= n4) return;
    float4 v = ((const float4*)in)[i];
    unsigned short o0 = f2bf(v.x), o1 = f2bf(v.y), o2 = f2bf(v.z), o3 = f2bf(v.w);
    unsigned long long packed = (unsigned long long)o0 | ((unsigned long long)o1 << 16)
        | ((unsigned long long)o2 << 32) | ((unsigned long long)o3 << 48);
    *(unsigned long long*)(out + (size_t)i * 4) = packed;
}

// ---------------- W[K][N] fp32 -> WT[N][K] bf16 ----------------
__global__ void k_wtrans(const float* __restrict__ W, unsigned short* __restrict__ WT, int K, int N) {
    __shared__ float t[32][33];
    int n0 = blockIdx.x * 32, k0 = blockIdx.y * 32;
    int tx = threadIdx.x, ty = threadIdx.y; // (32,8)
#pragma unroll
    for (int i = 0; i < 4; ++i)
        t[ty + i * 8][tx] = W[(size_t)(k0 + ty + i * 8) * N + n0 + tx];
    __syncthreads();
#pragma unroll
    for (int i = 0; i < 4; ++i)
        WT[(size_t)(n0 + ty + i * 8) * K + k0 + tx] = f2bf(t[tx][ty + i * 8]);
}

// ---------------- extract V head-major transposed: vt[bh][d][t] ----------------
__global__ void k_prep_vt(const unsigned short* __restrict__ qkv, unsigned short* __restrict__ vt) {
    int bh = blockIdx.y; int b = bh >> 4, h = bh & 15;
    int t0 = blockIdx.x * 64;
    __shared__ unsigned short tile[64][72];
    int tid = threadIdx.x;
    int r = tid >> 3;          // 0..31
    int c = (tid & 7) * 8;     // 0..56
#pragma unroll
    for (int rr = 0; rr < 64; rr += 32) {
        const unsigned short* src = qkv + (size_t)(b * T_ + t0 + r + rr) * C3_ + 2 * C_ + h * D_ + c;
        short8 v = *(const short8*)src;
#pragma unroll
        for (int j = 0; j < 8; ++j) tile[r + rr][c + j] = (unsigned short)v[j];
    }
    __syncthreads();
#pragma unroll
    for (int rr = 0; rr < 64; rr += 32) {
        int d = r + rr;
        short8 sv;
#pragma unroll
        for (int j = 0; j < 8; ++j) sv[j] = (short)tile[c + j][d];
        *(short8*)(vt + (size_t)bh * D_ * T_ + (size_t)d * T_ + t0 + c) = sv;
    }
}

// ---------------- GEMM (BM=256): C[M][N] = A @ BT^T + bias ----------------
// BM=256, BN=128, BK=32, 256 threads (4 waves: 2M x 2N), per-wave output 128x64.
// 3-buffer LDS pipeline (24KB/buf = 72KB), counted vmcnt(6), raw s_barrier.
// Swizzle for 64B rows: slot ^= ((row>>1)&3) via pre-swizzled global source.
// XCD-chunked block swizzle. OUT_BF16 path scales cols [0,1024) by QK_SCALE.
template<bool OUT_BF16>
__global__ __launch_bounds__(256, 2) void k_gemm_bt(const unsigned short* __restrict__ A,
                                                    const unsigned short* __restrict__ BT,
                                                    const float* __restrict__ bias,
                                                    unsigned short* __restrict__ outb,
                                                    float* __restrict__ outf,
                                                    int M, int N, int K) {
    __shared__ __align__(16) char arena[73728];
    int tid = threadIdx.x;
    int w = tid >> 6, lane = tid & 63;
    int wrow = w >> 1, wcol = w & 1;

    int lin = blockIdx.y * gridDim.x + blockIdx.x;
    int nwg8 = (gridDim.x * gridDim.y) >> 3;
    int newlin = (lin & 7) * nwg8 + (lin >> 3);
    int bx = newlin % gridDim.x;
    int by = newlin / gridDim.x;
    int m0 = by * 256, n0 = bx * 128;

    int lr = lane & 15, lg = lane >> 4;

    f32x4 acc[8][4] = {};

    int scb = ((tid & 3) << 4) ^ (((tid >> 3) & 3) << 4);
    int grow = tid >> 2;
    const char* sA[4];
    const char* sB[2];
#pragma unroll
    for (int rr = 0; rr < 4; ++rr)
        sA[rr] = (const char*)A + (size_t)(m0 + grow + rr * 64) * K * 2 + scb;
#pragma unroll
    for (int rr = 0; rr < 2; ++rr)
        sB[rr] = (const char*)BT + (size_t)(n0 + grow + rr * 64) * K * 2 + scb;

    int inner = (lg * 16) ^ (((lr >> 1) & 3) << 4);
    int aoff = wrow * 8192 + lr * 64 + inner;           // A frag: +i*1024
    int boff = 16384 + wcol * 4096 + lr * 64 + inner;   // B frag: +j*1024

#define GSTAGE(OFS)                                                                                 \
    {                                                                                               \
        _Pragma("unroll")                                                                           \
        for (int rr = 0; rr < 4; ++rr) {                                                            \
            __builtin_amdgcn_global_load_lds((const AS1 void*)sA[rr],                               \
                (AS3 void*)(arena + (OFS) + tid * 16 + rr * 4096), 16, 0, 0);                       \
            sA[rr] += 64;                                                                           \
        }                                                                                           \
        _Pragma("unroll")                                                                           \
        for (int rr = 0; rr < 2; ++rr) {                                                            \
            __builtin_amdgcn_global_load_lds((const AS1 void*)sB[rr],                               \
                (AS3 void*)(arena + (OFS) + 16384 + tid * 16 + rr * 4096), 16, 0, 0);               \
            sB[rr] += 64;                                                                           \
        }                                                                                           \
    }

#define GCOMPUTE(OFS)                                                                               \
    {                                                                                               \
        short8 af[8], bf[4];                                                                        \
        _Pragma("unroll")                                                                           \
        for (int i = 0; i < 8; ++i)                                                                 \
            af[i] = *(const short8*)(arena + (OFS) + aoff + i * 1024);                              \
        _Pragma("unroll")                                                                           \
        for (int j = 0; j < 4; ++j)                                                                 \
            bf[j] = *(const short8*)(arena + (OFS) + boff + j * 1024);                              \
        __builtin_amdgcn_s_setprio(1);                                                              \
        _Pragma("unroll")                                                                           \
        for (int i = 0; i < 8; ++i)                                                                 \
            _Pragma("unroll")                                                                       \
            for (int j = 0; j < 4; ++j)                                                             \
                acc[i][j] = __builtin_amdgcn_mfma_f32_16x16x32_bf16(af[i], bf[j], acc[i][j], 0, 0, 0); \
        __builtin_amdgcn_s_setprio(0);                                                              \
    }

    int NT = K >> 5;
    int ofs0 = 0, ofs1 = 24576, ofs2 = 49152;

    GSTAGE(ofs0);
    GSTAGE(ofs1);
    asm volatile("s_waitcnt vmcnt(6)" ::: "memory");
    __builtin_amdgcn_s_barrier();
    __builtin_amdgcn_sched_barrier(0);

    for (int t = 0; t < NT; ++t) {
        bool pf = (t + 2 < NT);
        if (pf) GSTAGE(ofs2);
        GCOMPUTE(ofs0);
        if (pf) { asm volatile("s_waitcnt vmcnt(6)" ::: "memory"); }
        else    { asm volatile("s_waitcnt vmcnt(0)" ::: "memory"); }
        __builtin_amdgcn_s_barrier();
        __builtin_amdgcn_sched_barrier(0);
        int tmp = ofs0; ofs0 = ofs1; ofs1 = ofs2; ofs2 = tmp;
    }
#undef GSTAGE
#undef GCOMPUTE

#pragma unroll
    for (int i = 0; i < 8; ++i) {
        int row = m0 + wrow * 128 + i * 16 + lg * 4;
#pragma unroll
        for (int j = 0; j < 4; ++j) {
            int col = n0 + wcol * 64 + j * 16 + lr;
            float bv = bias[col];
#pragma unroll
            for (int r = 0; r < 4; ++r) {
                float v = acc[i][j][r] + bv;
                if (OUT_BF16) {
                    if (col < C_) v *= QK_SCALE;
                    outb[(size_t)(row + r) * N + col] = f2bf(v);
                } else {
                    outf[(size_t)(row + r) * N + col] = v;
                }
            }
        }
    }
}

// ---------------- GEMM (BM=128) for the proj GEMM: better occupancy at small grids ----------
// BM=128, BN=128, BK=32, 256 threads (4 waves: 2M x 2N), per-wave output 64x64.
// 3-buffer pipeline (16KB/buf = 48KB -> 3 blocks/CU), counted vmcnt(4), raw s_barrier.
// Same swizzle algebra as BM=256 (XOR key (row>>1)&3 invariant under row+64).
__global__ __launch_bounds__(256, 3) void k_gemm_bt128(const unsigned short* __restrict__ A,
                                                       const unsigned short* __restrict__ BT,
                                                       const float* __restrict__ bias,
                                                       float* __restrict__ outf,
                                                       int M, int N, int K) {
    __shared__ __align__(16) char arena[49152];
    int tid = threadIdx.x;
    int w = tid >> 6, lane = tid & 63;
    int wrow = w >> 1, wcol = w & 1;

    int lin = blockIdx.y * gridDim.x + blockIdx.x;
    int nwg8 = (gridDim.x * gridDim.y) >> 3;
    int newlin = (lin & 7) * nwg8 + (lin >> 3);
    int bx = newlin % gridDim.x;
    int by = newlin / gridDim.x;
    int m0 = by * 128, n0 = bx * 128;

    int lr = lane & 15, lg = lane >> 4;

    f32x4 acc[4][4] = {};

    int scb = ((tid & 3) << 4) ^ (((tid >> 3) & 3) << 4);
    int grow = tid >> 2;
    const char* sA[2];
    const char* sB[2];
#pragma unroll
    for (int rr = 0; rr < 2; ++rr) {
        sA[rr] = (const char*)A + (size_t)(m0 + grow + rr * 64) * K * 2 + scb;
        sB[rr] = (const char*)BT + (size_t)(n0 + grow + rr * 64) * K * 2 + scb;
    }

    int inner = (lg * 16) ^ (((lr >> 1) & 3) << 4);
    int aoff = wrow * 4096 + lr * 64 + inner;          // A frag: +i*1024
    int boff = 8192 + wcol * 4096 + lr * 64 + inner;   // B frag: +j*1024

#define GSTAGE(OFS)                                                                                 \
    {                                                                                               \
        _Pragma("unroll")                                                                           \
        for (int rr = 0; rr < 2; ++rr) {                                                            \
            __builtin_amdgcn_global_load_lds((const AS1 void*)sA[rr],                               \
                (AS3 void*)(arena + (OFS) + tid * 16 + rr * 4096), 16, 0, 0);                       \
            sA[rr] += 64;                                                                           \
            __builtin_amdgcn_global_load_lds((const AS1 void*)sB[rr],                               \
                (AS3 void*)(arena + (OFS) + 8192 + tid * 16 + rr * 4096), 16, 0, 0);                \
            sB[rr] += 64;                                                                           \
        }                                                                                           \
    }

#define GCOMPUTE(OFS)                                                                               \
    {                                                                                               \
        short8 af[4], bf[4];                                                                        \
        _Pragma("unroll")                                                                           \
        for (int i = 0; i < 4; ++i)                                                                 \
            af[i] = *(const short8*)(arena + (OFS) + aoff + i * 1024);                              \
        _Pragma("unroll")                                                                           \
        for (int j = 0; j < 4; ++j)                                                                 \
            bf[j] = *(const short8*)(arena + (OFS) + boff + j * 1024);                              \
        __builtin_amdgcn_s_setprio(1);                                                              \
        _Pragma("unroll")                                                                           \
        for (int i = 0; i < 4; ++i)                                                                 \
            _Pragma("unroll")                                                                       \
            for (int j = 0; j < 4; ++j)                                                             \
                acc[i][j] = __builtin_amdgcn_mfma_f32_16x16x32_bf16(af[i], bf[j], acc[i][j], 0, 0, 0); \
        __builtin_amdgcn_s_setprio(0);                                                              \
    }

    int NT = K >> 5;
    int ofs0 = 0, ofs1 = 16384, ofs2 = 32768;

    GSTAGE(ofs0);
    GSTAGE(ofs1);
    asm volatile("s_waitcnt vmcnt(4)" ::: "memory");
    __builtin_amdgcn_s_barrier();
    __builtin_amdgcn_sched_barrier(0);

    for (int t = 0; t < NT; ++t) {
        bool pf = (t + 2 < NT);
        if (pf) GSTAGE(ofs2);
        GCOMPUTE(ofs0);
        if (pf) { asm volatile("s_waitcnt vmcnt(4)" ::: "memory"); }
        else    { asm volatile("s_waitcnt vmcnt(0)" ::: "memory"); }
        __builtin_amdgcn_s_barrier();
        __builtin_amdgcn_sched_barrier(0);
        int tmp = ofs0; ofs0 = ofs1; ofs1 = ofs2; ofs2 = tmp;
    }
#undef GSTAGE
#undef GCOMPUTE

#pragma unroll
    for (int i = 0; i < 4; ++i) {
        int row = m0 + wrow * 64 + i * 16 + lg * 4;
#pragma unroll
        for (int j = 0; j < 4; ++j) {
            int col = n0 + wcol * 64 + j * 16 + lr;
            float bv = bias[col];
#pragma unroll
            for (int r = 0; r < 4; ++r)
                outf[(size_t)(row + r) * N + col] = acc[i][j][r] + bv;
        }
    }
}

// ---------------- causal flash attention (swapped QK^T, no-max softmax) ----------------
// LDS arena layout (bytes):
//   [0,8192)      K buf0      [8192,16384)   K buf1
//   [16384,24576) V buf0      [24576,32768)  V buf1
//   [32768,40960) P per-wave (w*2048), conflict-free half-parity swizzle
__global__ __launch_bounds__(256, 4) void k_attn(const unsigned short* __restrict__ qkv,
                                                 const unsigned short* __restrict__ vt,
                                                 unsigned short* __restrict__ y) {
    __shared__ __align__(16) char arena[40960];
    int tid = threadIdx.x;
    int w = tid >> 6, lane = tid & 63;
    int lr = lane & 15, lg = lane >> 4;

    // bijective XCD-chunk swizzle (1024 % 8 == 0)
    int bid = blockIdx.x;
    int bid2 = (bid & 7) * 128 + (bid >> 3);
    int bh = bid2 >> 4, pair = bid2 & 15;
    int b = bh >> 4, h = bh & 15;

    const unsigned short* kbase = qkv + (size_t)(b * T_) * C3_ + C_ + h * D_;
    const unsigned short* vtb = vt + (size_t)bh * D_ * T_;

    // --- precomputed LDS addresses (tile-invariant) ---
    int sw_ = (lr & 7) << 4;
    int RB0 = lr * 128 + ((lg * 16) ^ sw_);   // K/V frag base (imm: arrayoff + buf + j*2048)
    int RB1 = RB0 ^ 64;
    int jl = (lr >> 1) & 3;
    int pbase = 32768 + w * 2048 + lr * 128
              + ((((lg >> 1) ^ (lr & 1)) << 4) | (((lg & 1) ^ (lr >> 3)) << 3));
    int pwa[4];
#pragma unroll
    for (int j = 0; j < 4; ++j) pwa[j] = pbase + ((j ^ jl) << 5);
    // P A-frag read addresses: XOR for the 64-offset (bit 6 lives inside the
    // swizzled column field — ADDITION WOULD CARRY into the row bits), plus
    // half-swap (+8, never carries: bit 3 of prd0 is 0) baked into the address.
    int prd0 = 32768 + w * 2048 + lr * 128 + ((lg ^ (lr & 7)) << 4);
    int prd1 = prd0 ^ 64;
    int hs = lr & 8;
    int prA0a = prd0 + hs,       prA0b = prd0 + (8 ^ hs);
    int prA1a = prd1 + hs,       prA1b = prd1 + (8 ^ hs);

    // --- global stage sources (loop-carried pointers) ---
    int row0 = tid >> 3, row1 = 32 + (tid >> 3);
    int scol0 = ((tid & 7) << 4) ^ ((row0 & 7) << 4);
    int scol1 = ((tid & 7) << 4) ^ ((row1 & 7) << 4);

    const char *sK0, *sK1, *sV0, *sV1;

#define ASTAGE(LDSOFF)                                                                                  \
    {                                                                                                   \
        __builtin_amdgcn_global_load_lds((const AS1 void*)sK0, (AS3 void*)(arena + (LDSOFF) + w * 1024), 16, 0, 0);          \
        __builtin_amdgcn_global_load_lds((const AS1 void*)sK1, (AS3 void*)(arena + (LDSOFF) + 4096 + w * 1024), 16, 0, 0);   \
        __builtin_amdgcn_global_load_lds((const AS1 void*)sV0, (AS3 void*)(arena + 16384 + (LDSOFF) + w * 1024), 16, 0, 0);  \
        __builtin_amdgcn_global_load_lds((const AS1 void*)sV1, (AS3 void*)(arena + 16384 + (LDSOFF) + 4096 + w * 1024), 16, 0, 0); \
        sK0 += 64 * C3_ * 2; sK1 += 64 * C3_ * 2; sV0 += 128; sV1 += 128;                               \
    }

#define ACOMPUTE(LDSOFF, KT)                                                                            \
    {                                                                                                   \
        f32x4 s[4];                                                                                     \
        __builtin_amdgcn_s_setprio(1);                                                                  \
        _Pragma("unroll")                                                                               \
        for (int j = 0; j < 4; ++j) {                                                                   \
            short8 kf0 = *(const short8*)(arena + RB0 + (LDSOFF) + j * 2048);                           \
            short8 kf1 = *(const short8*)(arena + RB1 + (LDSOFF) + j * 2048);                           \
            f32x4 z = {};                                                                               \
            z = __builtin_amdgcn_mfma_f32_16x16x32_bf16(kf0, qf0, z, 0, 0, 0);                          \
            s[j] = __builtin_amdgcn_mfma_f32_16x16x32_bf16(kf1, qf1, z, 0, 0, 0);                       \
        }                                                                                               \
        __builtin_amdgcn_s_setprio(0);                                                                  \
        if ((KT) == ntiles - 1) {                                                                       \
            int kb = (KT) * 64 + lg * 4 - qv;                                                           \
            _Pragma("unroll")                                                                           \
            for (int j = 0; j < 4; ++j)                                                                 \
                _Pragma("unroll")                                                                       \
                for (int r = 0; r < 4; ++r)                                                             \
                    if (kb + j * 16 + r > 0) s[j][r] = -INFINITY;                                       \
        }                                                                                               \
        _Pragma("unroll")                                                                               \
        for (int j = 0; j < 4; ++j)                                                                     \
            _Pragma("unroll")                                                                           \
            for (int r = 0; r < 4; ++r) {                                                               \
                float pv = __builtin_amdgcn_exp2f(s[j][r]);                                             \
                s[j][r] = pv;                                                                           \
                ls += pv;                                                                               \
            }                                                                                           \
        _Pragma("unroll")                                                                               \
        for (int j = 0; j < 4; ++j) {                                                                   \
            uint2v W;                                                                                   \
            W[0] = pk_bf16(s[j][0], s[j][1]);                                                           \
            W[1] = pk_bf16(s[j][2], s[j][3]);                                                           \
            *(uint2v*)(arena + pwa[j]) = W;                                                             \
        }                                                                                               \
        short4v l0 = *(const short4v*)(arena + prA0a);                                                  \
        short4v h0 = *(const short4v*)(arena + prA0b);                                                  \
        short4v l1 = *(const short4v*)(arena + prA1a);                                                  \
        short4v h1 = *(const short4v*)(arena + prA1b);                                                  \
        short8 pa0 = __builtin_shufflevector(l0, h0, 0, 1, 2, 3, 4, 5, 6, 7);                           \
        short8 pa1 = __builtin_shufflevector(l1, h1, 0, 1, 2, 3, 4, 5, 6, 7);                           \
        __builtin_amdgcn_s_setprio(1);                                                                  \
        _Pragma("unroll")                                                                               \
        for (int dt = 0; dt < 4; ++dt) {                                                                \
            short8 vf0 = *(const short8*)(arena + RB0 + 16384 + (LDSOFF) + dt * 2048);                  \
            short8 vf1 = *(const short8*)(arena + RB1 + 16384 + (LDSOFF) + dt * 2048);                  \
            o[dt] = __builtin_amdgcn_mfma_f32_16x16x32_bf16(pa0, vf0, o[dt], 0, 0, 0);                  \
            o[dt] = __builtin_amdgcn_mfma_f32_16x16x32_bf16(pa1, vf1, o[dt], 0, 0, 0);                  \
        }                                                                                               \
        __builtin_amdgcn_s_setprio(0);                                                                  \
    }

#pragma unroll 1
    for (int half = 0; half < 2; ++half) {
        int qt = half ? (31 - pair) : pair;
        int q0 = qt * 64;
        int ntiles = qt + 1;

        const unsigned short* qrow = qkv + (size_t)(b * T_ + q0 + w * 16 + lr) * C3_ + h * D_;
        short8 qf0 = *(const short8*)(qrow + lg * 8);
        short8 qf1 = *(const short8*)(qrow + 32 + lg * 8);

        f32x4 o[4] = {};
        float ls = 0.f;    // in-lane partial of unnormalized row-sum (q = q0 + w*16 + lr)
        int qv = q0 + w * 16 + lr;

        sK0 = (const char*)(kbase + (size_t)row0 * C3_) + scol0;
        sK1 = (const char*)(kbase + (size_t)row1 * C3_) + scol1;
        sV0 = (const char*)(vtb + (size_t)row0 * T_) + scol0;
        sV1 = (const char*)(vtb + (size_t)row1 * T_) + scol1;

        ASTAGE(0);
        asm volatile("s_waitcnt vmcnt(0)" ::: "memory");
        __syncthreads();

#pragma unroll 1
        for (int kt = 0; kt < ntiles; kt += 2) {
            if (kt + 1 < ntiles) ASTAGE(8192);
            ACOMPUTE(0, kt);
            asm volatile("s_waitcnt vmcnt(0)" ::: "memory");
            __syncthreads();
            if (kt + 1 < ntiles) {
                if (kt + 2 < ntiles) ASTAGE(0);
                ACOMPUTE(8192, kt + 1);
                asm volatile("s_waitcnt vmcnt(0)" ::: "memory");
                __syncthreads();
            }
        }

        // ---- combine lg-partials of ls, normalize + store ----
        ls += __shfl_xor(ls, 16);
        ls += __shfl_xor(ls, 32);
#pragma unroll
        for (int r = 0; r < 4; ++r) {
            float lst = __shfl(ls, lg * 4 + r, 64);
            float inv = 1.0f / lst;
            int q = q0 + w * 16 + lg * 4 + r;
            unsigned short* yrow = y + (size_t)(b * T_ + q) * C_ + h * D_;
#pragma unroll
            for (int dt = 0; dt < 4; ++dt)
                yrow[dt * 16 + lr] = f2bf(o[dt][r] * inv);
        }
    }
#undef ASTAGE
#undef ACOMPUTE
}

extern "C" void kernel_launch(void* const* d_in, const int* in_sizes, int n_in,
                              void* d_out, int out_size, void* d_ws, size_t ws_size,
                              hipStream_t stream) {
    const float* x  = (const float*)d_in[0];
    const float* Wa = (const float*)d_in[1];
    const float* ba = (const float*)d_in[2];
    const float* Wp = (const float*)d_in[3];
    const float* bp = (const float*)d_in[4];
    float* out = (float*)d_out;

    char* ws = (char*)d_ws;
    unsigned short* xb  = (unsigned short*)(ws);                       // 16 MB
    unsigned short* wat = (unsigned short*)(ws + 16777216);            // 6 MB
    unsigned short* wpt = (unsigned short*)(ws + 23068672);            // 2 MB
    unsigned short* qkv = (unsigned short*)(ws + 25165824);            // 48 MB
    unsigned short* vt  = (unsigned short*)(ws + 75497472);            // 16 MB
    unsigned short* y   = xb;  // xb dead after GEMM1; reuse for attention output

    // x -> bf16
    k_cvt_bf16<<<8192, 256, 0, stream>>>(x, xb, (B_ * T_ * C_) / 4);
    // weights -> bf16 transposed
    k_wtrans<<<dim3(C3_ / 32, C_ / 32), dim3(32, 8), 0, stream>>>(Wa, wat, C_, C3_);
    k_wtrans<<<dim3(C_ / 32, C_ / 32), dim3(32, 8), 0, stream>>>(Wp, wpt, C_, C_);
    // qkv = x @ W_attn + b_attn   (bf16 out, Q pre-scaled)
    k_gemm_bt<true><<<dim3(C3_ / 128, (B_ * T_) / 256), 256, 0, stream>>>(
        xb, wat, ba, qkv, nullptr, B_ * T_, C3_, C_);
    // v -> vt[bh][d][t]
    k_prep_vt<<<dim3(T_ / 64, B_ * H_), 256, 0, stream>>>(qkv, vt);
    // attention
    k_attn<<<1024, 256, 0, stream>>>(qkv, vt, y);
    // out = y @ W_proj + b_proj   (fp32 out, BM=128 variant: 512 blocks -> 2-3 blocks/CU)
    k_gemm_bt128<<<dim3(C_ / 128, (B_ * T_) / 128), 256, 0, stream>>>(
        y, wpt, bp, out, B_ * T_, C_, C_);
}

// Round 15
// 158.526 us; speedup vs baseline: 1.0729x; 1.0017x over previous
//
#include <hip/hip_runtime.h>
#include <stdint.h>

typedef __attribute__((ext_vector_type(8))) short short8;
typedef __attribute__((ext_vector_type(4))) short short4v;
typedef __attribute__((ext_vector_type(4))) float f32x4;
typedef __attribute__((ext_vector_type(2))) unsigned int uint2v;

#define B_ 4
#define T_ 2048
#define C_ 1024
#define H_ 16
#define D_ 64
#define C3_ 3072

#define AS1 __attribute__((address_space(1)))
#define AS3 __attribute__((address_space(3)))

#define QK_SCALE 0.18033688f   /* 1/sqrt(64) * log2(e), folded into Q at GEMM1 epilogue */

__device__ __forceinline__ unsigned short f2bf(float f) {
    union { float f; uint32_t u; } v; v.f = f;
    uint32_t r = v.u + 0x7FFFu + ((v.u >> 16) & 1u);
    return (unsigned short)(r >> 16);
}

__device__ __forceinline__ uint32_t pk_bf16(float lo, float hi) {
    uint32_t r;
    asm("v_cvt_pk_bf16_f32 %0, %1, %2" : "=v"(r) : "v"(lo), "v"(hi));
    return r;
}

// ---------------- fp32 -> bf16 elementwise ----------------
__global__ void k_cvt_bf16(const float* __restrict__ in, unsigned short* __restrict__ out, int n4) {
    int i = blockIdx.x * blockDim.x + threadIdx.x;
    if (i >= n4) return;
    float4 v = ((const float4*)in)[i];
    unsigned short o0 = f2bf(v.x), o1 = f2bf(v.y), o2 = f2bf(v.z), o3 = f2bf(v.w);
    unsigned long long packed = (unsigned long long)o0 | ((unsigned long long)o1 << 16)
        | ((unsigned long long)o2 << 32) | ((unsigned long long)o3 << 48);
    *(unsigned long long*)(out + (size_t)i * 4) = packed;
}

// ---------------- W[K][N] fp32 -> WT[N][K] bf16 ----------------
__global__ void k_wtrans(const float* __restrict__ W, unsigned short* __restrict__ WT, int K, int N) {
    __shared__ float t[32][33];
    int n0 = blockIdx.x * 32, k0 = blockIdx.y * 32;
    int tx = threadIdx.x, ty = threadIdx.y; // (32,8)
#pragma unroll
    for (int i = 0; i < 4; ++i)
        t[ty + i * 8][tx] = W[(size_t)(k0 + ty + i * 8) * N + n0 + tx];
    __syncthreads();
#pragma unroll
    for (int i = 0; i < 4; ++i)
        WT[(size_t)(n0 + ty + i * 8) * K + k0 + tx] = f2bf(t[tx][ty + i * 8]);
}

// ---------------- extract V head-major transposed: vt[bh][d][t] ----------------
__global__ void k_prep_vt(const unsigned short* __restrict__ qkv, unsigned short* __restrict__ vt) {
    int bh = blockIdx.y; int b = bh >> 4, h = bh & 15;
    int t0 = blockIdx.x * 64;
    __shared__ unsigned short tile[64][72];
    int tid = threadIdx.x;
    int r = tid >> 3;          // 0..31
    int c = (tid & 7) * 8;     // 0..56
#pragma unroll
    for (int rr = 0; rr < 64; rr += 32) {
        const unsigned short* src = qkv + (size_t)(b * T_ + t0 + r + rr) * C3_ + 2 * C_ + h * D_ + c;
        short8 v = *(const short8*)src;
#pragma unroll
        for (int j = 0; j < 8; ++j) tile[r + rr][c + j] = (unsigned short)v[j];
    }
    __syncthreads();
#pragma unroll
    for (int rr = 0; rr < 64; rr += 32) {
        int d = r + rr;
        short8 sv;
#pragma unroll
        for (int j = 0; j < 8; ++j) sv[j] = (short)tile[c + j][d];
        *(short8*)(vt + (size_t)bh * D_ * T_ + (size_t)d * T_ + t0 + c) = sv;
    }
}

// ---------------- GEMM (BM=256): C[M][N] = A @ BT^T + bias ----------------
template<bool OUT_BF16>
__global__ __launch_bounds__(256, 2) void k_gemm_bt(const unsigned short* __restrict__ A,
                                                    const unsigned short* __restrict__ BT,
                                                    const float* __restrict__ bias,
                                                    unsigned short* __restrict__ outb,
                                                    float* __restrict__ outf,
                                                    int M, int N, int K) {
    __shared__ __align__(16) char arena[73728];
    int tid = threadIdx.x;
    int w = tid >> 6, lane = tid & 63;
    int wrow = w >> 1, wcol = w & 1;

    int lin = blockIdx.y * gridDim.x + blockIdx.x;
    int nwg8 = (gridDim.x * gridDim.y) >> 3;
    int newlin = (lin & 7) * nwg8 + (lin >> 3);
    int bx = newlin % gridDim.x;
    int by = newlin / gridDim.x;
    int m0 = by * 256, n0 = bx * 128;

    int lr = lane & 15, lg = lane >> 4;

    f32x4 acc[8][4] = {};

    int scb = ((tid & 3) << 4) ^ (((tid >> 3) & 3) << 4);
    int grow = tid >> 2;
    const char* sA[4];
    const char* sB[2];
#pragma unroll
    for (int rr = 0; rr < 4; ++rr)
        sA[rr] = (const char*)A + (size_t)(m0 + grow + rr * 64) * K * 2 + scb;
#pragma unroll
    for (int rr = 0; rr < 2; ++rr)
        sB[rr] = (const char*)BT + (size_t)(n0 + grow + rr * 64) * K * 2 + scb;

    int inner = (lg * 16) ^ (((lr >> 1) & 3) << 4);
    int aoff = wrow * 8192 + lr * 64 + inner;           // A frag: +i*1024
    int boff = 16384 + wcol * 4096 + lr * 64 + inner;   // B frag: +j*1024

#define GSTAGE(OFS)                                                                                 \
    {                                                                                               \
        _Pragma("unroll")                                                                           \
        for (int rr = 0; rr < 4; ++rr) {                                                            \
            __builtin_amdgcn_global_load_lds((const AS1 void*)sA[rr],                               \
                (AS3 void*)(arena + (OFS) + tid * 16 + rr * 4096), 16, 0, 0);                       \
            sA[rr] += 64;                                                                           \
        }                                                                                           \
        _Pragma("unroll")                                                                           \
        for (int rr = 0; rr < 2; ++rr) {                                                            \
            __builtin_amdgcn_global_load_lds((const AS1 void*)sB[rr],                               \
                (AS3 void*)(arena + (OFS) + 16384 + tid * 16 + rr * 4096), 16, 0, 0);               \
            sB[rr] += 64;                                                                           \
        }                                                                                           \
    }

#define GCOMPUTE(OFS)                                                                               \
    {                                                                                               \
        short8 af[8], bf[4];                                                                        \
        _Pragma("unroll")                                                                           \
        for (int i = 0; i < 8; ++i)                                                                 \
            af[i] = *(const short8*)(arena + (OFS) + aoff + i * 1024);                              \
        _Pragma("unroll")                                                                           \
        for (int j = 0; j < 4; ++j)                                                                 \
            bf[j] = *(const short8*)(arena + (OFS) + boff + j * 1024);                              \
        __builtin_amdgcn_s_setprio(1);                                                              \
        _Pragma("unroll")                                                                           \
        for (int i = 0; i < 8; ++i)                                                                 \
            _Pragma("unroll")                                                                       \
            for (int j = 0; j < 4; ++j)                                                             \
                acc[i][j] = __builtin_amdgcn_mfma_f32_16x16x32_bf16(af[i], bf[j], acc[i][j], 0, 0, 0); \
        __builtin_amdgcn_s_setprio(0);                                                              \
    }

    int NT = K >> 5;
    int ofs0 = 0, ofs1 = 24576, ofs2 = 49152;

    GSTAGE(ofs0);
    GSTAGE(ofs1);
    asm volatile("s_waitcnt vmcnt(6)" ::: "memory");
    __builtin_amdgcn_s_barrier();
    __builtin_amdgcn_sched_barrier(0);

    for (int t = 0; t < NT; ++t) {
        bool pf = (t + 2 < NT);
        if (pf) GSTAGE(ofs2);
        GCOMPUTE(ofs0);
        if (pf) { asm volatile("s_waitcnt vmcnt(6)" ::: "memory"); }
        else    { asm volatile("s_waitcnt vmcnt(0)" ::: "memory"); }
        __builtin_amdgcn_s_barrier();
        __builtin_amdgcn_sched_barrier(0);
        int tmp = ofs0; ofs0 = ofs1; ofs1 = ofs2; ofs2 = tmp;
    }
#undef GSTAGE
#undef GCOMPUTE

#pragma unroll
    for (int i = 0; i < 8; ++i) {
        int row = m0 + wrow * 128 + i * 16 + lg * 4;
#pragma unroll
        for (int j = 0; j < 4; ++j) {
            int col = n0 + wcol * 64 + j * 16 + lr;
            float bv = bias[col];
#pragma unroll
            for (int r = 0; r < 4; ++r) {
                float v = acc[i][j][r] + bv;
                if (OUT_BF16) {
                    if (col < C_) v *= QK_SCALE;
                    outb[(size_t)(row + r) * N + col] = f2bf(v);
                } else {
                    outf[(size_t)(row + r) * N + col] = v;
                }
            }
        }
    }
}

// ---------------- GEMM (BM=128) for the proj GEMM ----------
__global__ __launch_bounds__(256, 3) void k_gemm_bt128(const unsigned short* __restrict__ A,
                                                       const unsigned short* __restrict__ BT,
                                                       const float* __restrict__ bias,
                                                       float* __restrict__ outf,
                                                       int M, int N, int K) {
    __shared__ __align__(16) char arena[49152];
    int tid = threadIdx.x;
    int w = tid >> 6, lane = tid & 63;
    int wrow = w >> 1, wcol = w & 1;

    int lin = blockIdx.y * gridDim.x + blockIdx.x;
    int nwg8 = (gridDim.x * gridDim.y) >> 3;
    int newlin = (lin & 7) * nwg8 + (lin >> 3);
    int bx = newlin % gridDim.x;
    int by = newlin / gridDim.x;
    int m0 = by * 128, n0 = bx * 128;

    int lr = lane & 15, lg = lane >> 4;

    f32x4 acc[4][4] = {};

    int scb = ((tid & 3) << 4) ^ (((tid >> 3) & 3) << 4);
    int grow = tid >> 2;
    const char* sA[2];
    const char* sB[2];
#pragma unroll
    for (int rr = 0; rr < 2; ++rr) {
        sA[rr] = (const char*)A + (size_t)(m0 + grow + rr * 64) * K * 2 + scb;
        sB[rr] = (const char*)BT + (size_t)(n0 + grow + rr * 64) * K * 2 + scb;
    }

    int inner = (lg * 16) ^ (((lr >> 1) & 3) << 4);
    int aoff = wrow * 4096 + lr * 64 + inner;
    int boff = 8192 + wcol * 4096 + lr * 64 + inner;

#define GSTAGE(OFS)                                                                                 \
    {                                                                                               \
        _Pragma("unroll")                                                                           \
        for (int rr = 0; rr < 2; ++rr) {                                                            \
            __builtin_amdgcn_global_load_lds((const AS1 void*)sA[rr],                               \
                (AS3 void*)(arena + (OFS) + tid * 16 + rr * 4096), 16, 0, 0);                       \
            sA[rr] += 64;                                                                           \
            __builtin_amdgcn_global_load_lds((const AS1 void*)sB[rr],                               \
                (AS3 void*)(arena + (OFS) + 8192 + tid * 16 + rr * 4096), 16, 0, 0);                \
            sB[rr] += 64;                                                                           \
        }                                                                                           \
    }

#define GCOMPUTE(OFS)                                                                               \
    {                                                                                               \
        short8 af[4], bf[4];                                                                        \
        _Pragma("unroll")                                                                           \
        for (int i = 0; i < 4; ++i)                                                                 \
            af[i] = *(const short8*)(arena + (OFS) + aoff + i * 1024);                              \
        _Pragma("unroll")                                                                           \
        for (int j = 0; j < 4; ++j)                                                                 \
            bf[j] = *(const short8*)(arena + (OFS) + boff + j * 1024);                              \
        __builtin_amdgcn_s_setprio(1);                                                              \
        _Pragma("unroll")                                                                           \
        for (int i = 0; i < 4; ++i)                                                                 \
            _Pragma("unroll")                                                                       \
            for (int j = 0; j < 4; ++j)                                                             \
                acc[i][j] = __builtin_amdgcn_mfma_f32_16x16x32_bf16(af[i], bf[j], acc[i][j], 0, 0, 0); \
        __builtin_amdgcn_s_setprio(0);                                                              \
    }

    int NT = K >> 5;
    int ofs0 = 0, ofs1 = 16384, ofs2 = 32768;

    GSTAGE(ofs0);
    GSTAGE(ofs1);
    asm volatile("s_waitcnt vmcnt(4)" ::: "memory");
    __builtin_amdgcn_s_barrier();
    __builtin_amdgcn_sched_barrier(0);

    for (int t = 0; t < NT; ++t) {
        bool pf = (t + 2 < NT);
        if (pf) GSTAGE(ofs2);
        GCOMPUTE(ofs0);
        if (pf) { asm volatile("s_waitcnt vmcnt(4)" ::: "memory"); }
        else    { asm volatile("s_waitcnt vmcnt(0)" ::: "memory"); }
        __builtin_amdgcn_s_barrier();
        __builtin_amdgcn_sched_barrier(0);
        int tmp = ofs0; ofs0 = ofs1; ofs1 = ofs2; ofs2 = tmp;
    }
#undef GSTAGE
#undef GCOMPUTE

#pragma unroll
    for (int i = 0; i < 4; ++i) {
        int row = m0 + wrow * 64 + i * 16 + lg * 4;
#pragma unroll
        for (int j = 0; j < 4; ++j) {
            int col = n0 + wcol * 64 + j * 16 + lr;
            float bv = bias[col];
#pragma unroll
            for (int r = 0; r < 4; ++r)
                outf[(size_t)(row + r) * N + col] = acc[i][j][r] + bv;
        }
    }
}

// ---------------- causal flash attention: QBLK=128 (2 q-frags/wave) ----------------
// LDS arena (48KB -> 3 blocks/CU):
//   [0,16384)     K bufs 0/1 (8KB each)
//   [16384,32768) V bufs 0/1
//   [32768,49152) P per-wave (w*4096), per-qf +2048, half-parity swizzle
// Grid 512 blocks (8 q-pairs x 64 bh), uniform 34 kv-tiles/block.
__global__ __launch_bounds__(256, 3) void k_attn(const unsigned short* __restrict__ qkv,
                                                 const unsigned short* __restrict__ vt,
                                                 unsigned short* __restrict__ y) {
    __shared__ __align__(16) char arena[49152];
    int tid = threadIdx.x;
    int w = tid >> 6, lane = tid & 63;
    int lr = lane & 15, lg = lane >> 4;

    // bijective XCD-chunk swizzle (512 % 8 == 0)
    int bid = blockIdx.x;
    int bid2 = (bid & 7) * 64 + (bid >> 3);
    int bh = bid2 >> 3, pair = bid2 & 7;
    int b = bh >> 4, h = bh & 15;

    const unsigned short* kbase = qkv + (size_t)(b * T_) * C3_ + C_ + h * D_;
    const unsigned short* vtb = vt + (size_t)bh * D_ * T_;

    // --- K/V frag addresses (tile-invariant) ---
    int sw_ = (lr & 7) << 4;
    int RB0 = lr * 128 + ((lg * 16) ^ sw_);   // + LDSOFF; V: +16384
    int RB1 = RB0 ^ 64;

    // --- P addresses (qf=0 set; qf=1 = +2048 folds into ds imm offset) ---
    int jl = (lr >> 1) & 3;
    int pbase = 32768 + w * 4096 + lr * 128
              + ((((lg >> 1) ^ (lr & 1)) << 4) | (((lg & 1) ^ (lr >> 3)) << 3));
    int pwa[4];
#pragma unroll
    for (int j = 0; j < 4; ++j) pwa[j] = pbase + ((j ^ jl) << 5);
    int prd0 = 32768 + w * 4096 + lr * 128 + ((lg ^ (lr & 7)) << 4);
    int prd1 = prd0 ^ 64;     // XOR not ADD: bit6 is inside the swizzled field
    int hs = lr & 8;
    int prA0a = prd0 + hs, prA0b = prd0 + (8 ^ hs);
    int prA1a = prd1 + hs, prA1b = prd1 + (8 ^ hs);

    // --- global stage sources ---
    int row0 = tid >> 3, row1 = 32 + (tid >> 3);
    int scol0 = ((tid & 7) << 4) ^ ((row0 & 7) << 4);
    int scol1 = ((tid & 7) << 4) ^ ((row1 & 7) << 4);

    const char *sK0, *sK1, *sV0, *sV1;

#define ASTAGE(LDSOFF)                                                                                  \
    {                                                                                                   \
        __builtin_amdgcn_global_load_lds((const AS1 void*)sK0, (AS3 void*)(arena + (LDSOFF) + w * 1024), 16, 0, 0);          \
        __builtin_amdgcn_global_load_lds((const AS1 void*)sK1, (AS3 void*)(arena + (LDSOFF) + 4096 + w * 1024), 16, 0, 0);   \
        __builtin_amdgcn_global_load_lds((const AS1 void*)sV0, (AS3 void*)(arena + 16384 + (LDSOFF) + w * 1024), 16, 0, 0);  \
        __builtin_amdgcn_global_load_lds((const AS1 void*)sV1, (AS3 void*)(arena + 16384 + (LDSOFF) + 4096 + w * 1024), 16, 0, 0); \
        sK0 += 64 * C3_ * 2; sK1 += 64 * C3_ * 2; sV0 += 128; sV1 += 128;                               \
    }

#define ACOMPUTE(LDSOFF, KT)                                                                            \
    {                                                                                                   \
        f32x4 s0[4], s1[4];                                                                             \
        __builtin_amdgcn_s_setprio(1);                                                                  \
        _Pragma("unroll")                                                                               \
        for (int j = 0; j < 4; ++j) {                                                                   \
            short8 kf0 = *(const short8*)(arena + RB0 + (LDSOFF) + j * 2048);                           \
            short8 kf1 = *(const short8*)(arena + RB1 + (LDSOFF) + j * 2048);                           \
            f32x4 z0 = {}, z1 = {};                                                                     \
            z0 = __builtin_amdgcn_mfma_f32_16x16x32_bf16(kf0, qA0, z0, 0, 0, 0);                        \
            s0[j] = __builtin_amdgcn_mfma_f32_16x16x32_bf16(kf1, qA1, z0, 0, 0, 0);                     \
            z1 = __builtin_amdgcn_mfma_f32_16x16x32_bf16(kf0, qB0, z1, 0, 0, 0);                        \
            s1[j] = __builtin_amdgcn_mfma_f32_16x16x32_bf16(kf1, qB1, z1, 0, 0, 0);                     \
        }                                                                                               \
        __builtin_amdgcn_s_setprio(0);                                                                  \
        if ((KT) >= ntiles - 2) {                                                                       \
            int kb0 = (KT) * 64 + lg * 4 - qv0;                                                         \
            _Pragma("unroll")                                                                           \
            for (int j = 0; j < 4; ++j)                                                                 \
                _Pragma("unroll")                                                                       \
                for (int r = 0; r < 4; ++r) {                                                           \
                    if (kb0 + j * 16 + r > 0)      s0[j][r] = -INFINITY;                                \
                    if (kb0 - 16 + j * 16 + r > 0) s1[j][r] = -INFINITY;  /* s1 rows at qv0+16 */       \
                }                                                                                       \
        }                                                                                               \
        _Pragma("unroll")                                                                               \
        for (int j = 0; j < 4; ++j)                                                                     \
            _Pragma("unroll")                                                                           \
            for (int r = 0; r < 4; ++r) {                                                               \
                float p0 = __builtin_amdgcn_exp2f(s0[j][r]);                                            \
                float p1 = __builtin_amdgcn_exp2f(s1[j][r]);                                            \
                s0[j][r] = p0; ls0 += p0;                                                               \
                s1[j][r] = p1; ls1 += p1;                                                               \
            }                                                                                           \
        _Pragma("unroll")                                                                               \
        for (int j = 0; j < 4; ++j) {                                                                   \
            uint2v W0, W1;                                                                              \
            W0[0] = pk_bf16(s0[j][0], s0[j][1]);                                                        \
            W0[1] = pk_bf16(s0[j][2], s0[j][3]);                                                        \
            W1[0] = pk_bf16(s1[j][0], s1[j][1]);                                                        \
            W1[1] = pk_bf16(s1[j][2], s1[j][3]);                                                        \
            *(uint2v*)(arena + pwa[j]) = W0;                                                            \
            *(uint2v*)(arena + pwa[j] + 2048) = W1;                                                     \
        }                                                                                               \
        short4v l00 = *(const short4v*)(arena + prA0a);                                                 \
        short4v h00 = *(const short4v*)(arena + prA0b);                                                 \
        short4v l01 = *(const short4v*)(arena + prA1a);                                                 \
        short4v h01 = *(const short4v*)(arena + prA1b);                                                 \
        short4v l10 = *(const short4v*)(arena + prA0a + 2048);                                          \
        short4v h10 = *(const short4v*)(arena + prA0b + 2048);                                          \
        short4v l11 = *(const short4v*)(arena + prA1a + 2048);                                          \
        short4v h11 = *(const short4v*)(arena + prA1b + 2048);                                          \
        short8 pa00 = __builtin_shufflevector(l00, h00, 0, 1, 2, 3, 4, 5, 6, 7);                        \
        short8 pa01 = __builtin_shufflevector(l01, h01, 0, 1, 2, 3, 4, 5, 6, 7);                        \
        short8 pa10 = __builtin_shufflevector(l10, h10, 0, 1, 2, 3, 4, 5, 6, 7);                        \
        short8 pa11 = __builtin_shufflevector(l11, h11, 0, 1, 2, 3, 4, 5, 6, 7);                        \
        __builtin_amdgcn_s_setprio(1);                                                                  \
        _Pragma("unroll")                                                                               \
        for (int dt = 0; dt < 4; ++dt) {                                                                \
            short8 vf0 = *(const short8*)(arena + RB0 + 16384 + (LDSOFF) + dt * 2048);                  \
            short8 vf1 = *(const short8*)(arena + RB1 + 16384 + (LDSOFF) + dt * 2048);                  \
            o0[dt] = __builtin_amdgcn_mfma_f32_16x16x32_bf16(pa00, vf0, o0[dt], 0, 0, 0);               \
            o0[dt] = __builtin_amdgcn_mfma_f32_16x16x32_bf16(pa01, vf1, o0[dt], 0, 0, 0);               \
            o1[dt] = __builtin_amdgcn_mfma_f32_16x16x32_bf16(pa10, vf0, o1[dt], 0, 0, 0);               \
            o1[dt] = __builtin_amdgcn_mfma_f32_16x16x32_bf16(pa11, vf1, o1[dt], 0, 0, 0);               \
        }                                                                                               \
        __builtin_amdgcn_s_setprio(0);                                                                  \
    }

#pragma unroll 1
    for (int half = 0; half < 2; ++half) {
        int qt = half ? (15 - pair) : pair;
        int q0 = qt * 128;
        int ntiles = 2 * qt + 2;

        const unsigned short* qrowA = qkv + (size_t)(b * T_ + q0 + w * 32 + lr) * C3_ + h * D_;
        const unsigned short* qrowB = qrowA + (size_t)16 * C3_;
        short8 qA0 = *(const short8*)(qrowA + lg * 8);
        short8 qA1 = *(const short8*)(qrowA + 32 + lg * 8);
        short8 qB0 = *(const short8*)(qrowB + lg * 8);
        short8 qB1 = *(const short8*)(qrowB + 32 + lg * 8);

        f32x4 o0[4] = {}, o1[4] = {};
        float ls0 = 0.f, ls1 = 0.f;
        int qv0 = q0 + w * 32 + lr;   // qf=0 row; qf=1 row = qv0+16

        sK0 = (const char*)(kbase + (size_t)row0 * C3_) + scol0;
        sK1 = (const char*)(kbase + (size_t)row1 * C3_) + scol1;
        sV0 = (const char*)(vtb + (size_t)row0 * T_) + scol0;
        sV1 = (const char*)(vtb + (size_t)row1 * T_) + scol1;

        ASTAGE(0);
        asm volatile("s_waitcnt vmcnt(0)" ::: "memory");
        __syncthreads();

#pragma unroll 1
        for (int kt = 0; kt < ntiles; kt += 2) {
            if (kt + 1 < ntiles) ASTAGE(8192);
            ACOMPUTE(0, kt);
            asm volatile("s_waitcnt vmcnt(0)" ::: "memory");
            __syncthreads();
            if (kt + 1 < ntiles) {
                if (kt + 2 < ntiles) ASTAGE(0);
                ACOMPUTE(8192, kt + 1);
                asm volatile("s_waitcnt vmcnt(0)" ::: "memory");
                __syncthreads();
            }
        }

        // ---- reduce ls over lg, normalize + store ----
        ls0 += __shfl_xor(ls0, 16); ls0 += __shfl_xor(ls0, 32);
        ls1 += __shfl_xor(ls1, 16); ls1 += __shfl_xor(ls1, 32);
#pragma unroll
        for (int r = 0; r < 4; ++r) {
            float l0 = __shfl(ls0, lg * 4 + r, 64);
            float l1 = __shfl(ls1, lg * 4 + r, 64);
            float i0 = 1.0f / l0, i1 = 1.0f / l1;
            int qa = q0 + w * 32 + lg * 4 + r;
            unsigned short* yrA = y + (size_t)(b * T_ + qa) * C_ + h * D_;
            unsigned short* yrB = yrA + (size_t)16 * C_;
#pragma unroll
            for (int dt = 0; dt < 4; ++dt) {
                yrA[dt * 16 + lr] = f2bf(o0[dt][r] * i0);
                yrB[dt * 16 + lr] = f2bf(o1[dt][r] * i1);
            }
        }
    }
#undef ASTAGE
#undef ACOMPUTE
}

extern "C" void kernel_launch(void* const* d_in, const int* in_sizes, int n_in,
                              void* d_out, int out_size, void* d_ws, size_t ws_size,
                              hipStream_t stream) {
    const float* x  = (const float*)d_in[0];
    const float* Wa = (const float*)d_in[1];
    const float* ba = (const float*)d_in[2];
    const float* Wp = (const float*)d_in[3];
    const float* bp = (const float*)d_in[4];
    float* out = (float*)d_out;

    char* ws = (char*)d_ws;
    unsigned short* xb  = (unsigned short*)(ws);                       // 16 MB
    unsigned short* wat = (unsigned short*)(ws + 16777216);            // 6 MB
    unsigned short* wpt = (unsigned short*)(ws + 23068672);            // 2 MB
    unsigned short* qkv = (unsigned short*)(ws + 25165824);            // 48 MB
    unsigned short* vt  = (unsigned short*)(ws + 75497472);            // 16 MB
    unsigned short* y   = xb;  // xb dead after GEMM1; reuse for attention output

    // x -> bf16
    k_cvt_bf16<<<8192, 256, 0, stream>>>(x, xb, (B_ * T_ * C_) / 4);
    // weights -> bf16 transposed
    k_wtrans<<<dim3(C3_ / 32, C_ / 32), dim3(32, 8), 0, stream>>>(Wa, wat, C_, C3_);
    k_wtrans<<<dim3(C_ / 32, C_ / 32), dim3(32, 8), 0, stream>>>(Wp, wpt, C_, C_);
    // qkv = x @ W_attn + b_attn   (bf16 out, Q pre-scaled)
    k_gemm_bt<true><<<dim3(C3_ / 128, (B_ * T_) / 256), 256, 0, stream>>>(
        xb, wat, ba, qkv, nullptr, B_ * T_, C3_, C_);
    // v -> vt[bh][d][t]
    k_prep_vt<<<dim3(T_ / 64, B_ * H_), 256, 0, stream>>>(qkv, vt);
    // attention (512 blocks: 8 pairs x 64 bh)
    k_attn<<<512, 256, 0, stream>>>(qkv, vt, y);
    // out = y @ W_proj + b_proj   (fp32 out, BM=128)
    k_gemm_bt128<<<dim3(C_ / 128, (B_ * T_) / 128), 256, 0, stream>>>(
        y, wpt, bp, out, B_ * T_, C_, C_);
}